// Round 7
// baseline (580.824 us; speedup 1.0000x reference)
//
#include <hip/hip_runtime.h>
#include <cmath>

#ifndef CAP0
#define CAP0 192   // max staged degree; Poisson(16) max ~45. Fallback path covers >CAP.
#endif

// ---------------- CSR build (by dst) ----------------
__global__ void k_hist(const int* __restrict__ dst, int* __restrict__ counts, int E) {
  int e = blockIdx.x * blockDim.x + threadIdx.x;
  if (e < E) atomicAdd(&counts[dst[e]], 1);
}

// inclusive scan within 256-blocks
__global__ void k_blockscan(const int* __restrict__ counts, int* __restrict__ partial,
                            int* __restrict__ bsums, int n) {
  __shared__ int buf[256];
  int tid = threadIdx.x;
  int i = blockIdx.x * 256 + tid;
  int v = (i < n) ? counts[i] : 0;
  buf[tid] = v;
  __syncthreads();
  for (int off = 1; off < 256; off <<= 1) {
    int t = (tid >= off) ? buf[tid - off] : 0;
    __syncthreads();
    buf[tid] += t;
    __syncthreads();
  }
  if (i < n) partial[i] = buf[tid];
  if (tid == 255) bsums[blockIdx.x] = buf[255];
}

// exclusive scan of block sums (nb <= 256), in place
__global__ void k_scansums(int* __restrict__ bsums, int nb) {
  __shared__ int buf[256];
  int tid = threadIdx.x;
  int v = (tid < nb) ? bsums[tid] : 0;
  buf[tid] = v;
  __syncthreads();
  for (int off = 1; off < 256; off <<= 1) {
    int t = (tid >= off) ? buf[tid - off] : 0;
    __syncthreads();
    buf[tid] += t;
    __syncthreads();
  }
  if (tid < nb) bsums[tid] = buf[tid] - v;
}

// indptr[i+1] = inclusive[i]; cursor[i] = exclusive[i] (= running insert ptr for scatter)
__global__ void k_addoff(const int* __restrict__ partial, const int* __restrict__ bsums,
                         const int* __restrict__ counts, int* __restrict__ indptr,
                         int* __restrict__ cursor, int n) {
  int i = blockIdx.x * blockDim.x + threadIdx.x;
  if (i == 0) indptr[0] = 0;
  if (i < n) {
    int incl = partial[i] + bsums[i >> 8];
    indptr[i + 1] = incl;
    cursor[i] = incl - counts[i];
  }
}

// NOTE: bucket order = atomic completion order (nondeterministic). Aggregation
// reorder shifts fp32 sums by ~1e-8 at the final output — accepted.
__global__ void k_scatter(const int* __restrict__ dst, int* __restrict__ cursor,
                          int* __restrict__ ecsr, int E) {
  int e = blockIdx.x * blockDim.x + threadIdx.x;
  if (e < E) {
    int pos = atomicAdd(&cursor[dst[e]], 1);
    ecsr[pos] = e;
  }
}

// ---------------- GEMM0 + fused attention dots (layer 0) ----------------
// f0[N,256] = x[N,128] @ W0[128,256]. R4 structure, 16 rows/block:
// per k: 1 coalesced W vload + 16 uniform x loads (SGPR) + 16 FMA.
// Same 4x32-k chunk associativity as R4 -> bitwise-identical row sums.
__global__ void k_gemm0(const float* __restrict__ x, const float* __restrict__ W0,
                        const float* __restrict__ al, const float* __restrict__ ar,
                        float* __restrict__ f0, float* __restrict__ el,
                        float* __restrict__ er, int N) {
  int col = threadIdx.x;            // 0..255 == h*32+d
  int row0 = blockIdx.x * 16;
  const float* xr[16];
#pragma unroll
  for (int r = 0; r < 16; ++r) {
    int row = row0 + r; if (row >= N) row = N - 1;
    xr[r] = x + (size_t)row * 128;  // block-uniform -> SGPR loads
  }
  float acc[4][16];
#pragma unroll
  for (int c = 0; c < 4; ++c)
#pragma unroll
    for (int r = 0; r < 16; ++r) acc[c][r] = 0.f;

#pragma unroll
  for (int c = 0; c < 4; ++c) {
    const float* Wc = W0 + (size_t)(c * 32) * 256 + col;
#pragma unroll 4
    for (int kk = 0; kk < 32; ++kk) {
      float w = Wc[kk * 256];
      int k = c * 32 + kk;
#pragma unroll
      for (int r = 0; r < 16; ++r) acc[c][r] = fmaf(xr[r][k], w, acc[c][r]);
    }
  }

  int h = col >> 5;
  float a_l = al[col], a_r = ar[col];
#pragma unroll
  for (int r = 0; r < 16; ++r) {
    int row = row0 + r;
    float f = (acc[0][r] + acc[1][r]) + (acc[2][r] + acc[3][r]);
    if (row < N) f0[(size_t)row * 256 + col] = f;
    float pl = f * a_l;
    float pr = f * a_r;
#pragma unroll
    for (int off = 16; off >= 1; off >>= 1) {
      pl += __shfl_xor(pl, off, 32);
      pr += __shfl_xor(pr, off, 32);
    }
    if ((col & 31) == 0 && row < N) {
      el[row * 8 + h] = pl;
      er[row * 8 + h] = pr;
    }
  }
}

// ---------------- fused edge kernel layer 0 ----------------
// one block = one dst node; phase 1: scores+softmax (8 heads x 32 lanes);
// phase 2: wave-wide float4 gather (one wave = one full 1 KB row), 4 loads
// in flight per wave (unroll x4, same FMA order -> bitwise identical), LDS reduce.
__global__ void k_fused0(const float* __restrict__ el, const float* __restrict__ er,
                         const float* __restrict__ f0, const int* __restrict__ indptr,
                         const int* __restrict__ ecsr, const int* __restrict__ src,
                         const float* __restrict__ b0, float* __restrict__ hout, int N) {
  __shared__ float s_w[CAP0 * 8];
  __shared__ int s_src[CAP0];
  __shared__ float s_red[4][256];
  int n = blockIdx.x;
  int t = threadIdx.x;
  int h = t >> 5, lane = t & 31;
  int s = indptr[n], e_ = indptr[n + 1];
  int deg = e_ - s;
  float er_h = er[n * 8 + h];

  if (deg <= CAP0) {
    // ---- phase 1: scores + segment softmax into s_w ----
    float m = -INFINITY;
    for (int i = lane; i < deg; i += 32) {
      int e = ecsr[s + i];
      int sn = src[e];
      if (h == 0) s_src[i] = sn;
      float v = el[sn * 8 + h] + er_h;
      v = v >= 0.f ? v : 0.2f * v;
      s_w[i * 8 + h] = v;
      m = fmaxf(m, v);
    }
#pragma unroll
    for (int off = 16; off >= 1; off >>= 1) m = fmaxf(m, __shfl_xor(m, off, 32));
    float sum = 0.f;
    for (int i = lane; i < deg; i += 32) {
      float a = expf(s_w[i * 8 + h] - m);
      s_w[i * 8 + h] = a;
      sum += a;
    }
#pragma unroll
    for (int off = 16; off >= 1; off >>= 1) sum += __shfl_xor(sum, off, 32);
    for (int i = lane; i < deg; i += 32) s_w[i * 8 + h] /= sum;   // IEEE div as reference
    __syncthreads();

    // ---- phase 2: gather. wave w handles edges w, w+4, w+8, ... ----
    int w = t >> 6;
    int l = t & 63;                  // float4 slot: dims 4l..4l+3
    int hh = l >> 3;                 // head of this slot
    float4 a4 = make_float4(0.f, 0.f, 0.f, 0.f);
    int i = w;
    for (; i + 12 < deg; i += 16) {  // 4 rows in flight
      float a0 = s_w[(i + 0) * 8 + hh];
      float a1 = s_w[(i + 4) * 8 + hh];
      float a2 = s_w[(i + 8) * 8 + hh];
      float a3 = s_w[(i + 12) * 8 + hh];
      float4 v0 = ((const float4*)(f0 + (size_t)s_src[i + 0] * 256))[l];
      float4 v1 = ((const float4*)(f0 + (size_t)s_src[i + 4] * 256))[l];
      float4 v2 = ((const float4*)(f0 + (size_t)s_src[i + 8] * 256))[l];
      float4 v3 = ((const float4*)(f0 + (size_t)s_src[i + 12] * 256))[l];
      a4.x = fmaf(a0, v0.x, a4.x); a4.y = fmaf(a0, v0.y, a4.y);
      a4.z = fmaf(a0, v0.z, a4.z); a4.w = fmaf(a0, v0.w, a4.w);
      a4.x = fmaf(a1, v1.x, a4.x); a4.y = fmaf(a1, v1.y, a4.y);
      a4.z = fmaf(a1, v1.z, a4.z); a4.w = fmaf(a1, v1.w, a4.w);
      a4.x = fmaf(a2, v2.x, a4.x); a4.y = fmaf(a2, v2.y, a4.y);
      a4.z = fmaf(a2, v2.z, a4.z); a4.w = fmaf(a2, v2.w, a4.w);
      a4.x = fmaf(a3, v3.x, a4.x); a4.y = fmaf(a3, v3.y, a4.y);
      a4.z = fmaf(a3, v3.z, a4.z); a4.w = fmaf(a3, v3.w, a4.w);
    }
    for (; i < deg; i += 4) {
      float a0 = s_w[i * 8 + hh];
      float4 v0 = ((const float4*)(f0 + (size_t)s_src[i] * 256))[l];
      a4.x = fmaf(a0, v0.x, a4.x); a4.y = fmaf(a0, v0.y, a4.y);
      a4.z = fmaf(a0, v0.z, a4.z); a4.w = fmaf(a0, v0.w, a4.w);
    }
    ((float4*)s_red[w])[l] = a4;
    __syncthreads();
    float o = ((s_red[0][t] + s_red[1][t]) + (s_red[2][t] + s_red[3][t])) + b0[t];
    hout[(size_t)n * 256 + t] = o > 0.f ? o : expm1f(o);   // jax.nn.elu
  } else {
    // 3-pass recompute fallback — block-uniform branch
    float m = -INFINITY;
    for (int i = lane; i < deg; i += 32) {
      float v = el[src[ecsr[s + i]] * 8 + h] + er_h;
      v = v >= 0.f ? v : 0.2f * v;
      m = fmaxf(m, v);
    }
#pragma unroll
    for (int off = 16; off >= 1; off >>= 1) m = fmaxf(m, __shfl_xor(m, off, 32));
    float sum = 0.f;
    for (int i = lane; i < deg; i += 32) {
      float v = el[src[ecsr[s + i]] * 8 + h] + er_h;
      v = v >= 0.f ? v : 0.2f * v;
      sum += expf(v - m);
    }
#pragma unroll
    for (int off = 16; off >= 1; off >>= 1) sum += __shfl_xor(sum, off, 32);
    float acc = 0.f;
    for (int i = 0; i < deg; ++i) {
      int sn = src[ecsr[s + i]];
      float v = el[sn * 8 + h] + er_h;
      v = v >= 0.f ? v : 0.2f * v;
      float a = expf(v - m) / sum;
      acc += a * f0[(size_t)sn * 256 + t];
    }
    float o = acc + b0[t];
    hout[(size_t)n * 256 + t] = o > 0.f ? o : expm1f(o);
  }
}

// ---------------- GEMM1 + fused attention dots (layer 1, H=1) ----------------
// [R4-exact] block = 8 rows x 32 cols, float4 h loads
__global__ void k_gemm1(const float* __restrict__ h, const float* __restrict__ W1,
                        const float* __restrict__ al, const float* __restrict__ ar,
                        float* __restrict__ f1, float* __restrict__ el,
                        float* __restrict__ er, int N) {
  int t = threadIdx.x;
  int r = t >> 5, col = t & 31;
  int row = blockIdx.x * 8 + r;
  int rr = row < N ? row : N - 1;
  const float* hr = h + (size_t)rr * 256;
  float c0 = 0.f, c1 = 0.f;
#pragma unroll 4
  for (int k4 = 0; k4 < 32; ++k4) {
    float4 hv = *(const float4*)(hr + k4 * 4);
    const float* wp = W1 + (size_t)(k4 * 4) * 32 + col;
    c0 = fmaf(hv.x, wp[0],  c0);
    c0 = fmaf(hv.y, wp[32], c0);
    c0 = fmaf(hv.z, wp[64], c0);
    c0 = fmaf(hv.w, wp[96], c0);
  }
#pragma unroll 4
  for (int k4 = 32; k4 < 64; ++k4) {
    float4 hv = *(const float4*)(hr + k4 * 4);
    const float* wp = W1 + (size_t)(k4 * 4) * 32 + col;
    c1 = fmaf(hv.x, wp[0],  c1);
    c1 = fmaf(hv.y, wp[32], c1);
    c1 = fmaf(hv.z, wp[64], c1);
    c1 = fmaf(hv.w, wp[96], c1);
  }
  float f = c0 + c1;
  float pl = f * al[col];
  float pr = f * ar[col];
#pragma unroll
  for (int off = 16; off >= 1; off >>= 1) {
    pl += __shfl_xor(pl, off, 32);
    pr += __shfl_xor(pr, off, 32);
  }
  if (row < N) {
    f1[(size_t)row * 32 + col] = f;
    if (col == 0) { el[row] = pl; er[row] = pr; }
  }
}

// ---------------- fused edge kernel layer 1 (H=1, D=32) ----------------
// block = 4 nodes x 64 lanes. agg: 8 edge-slots x 8 lanes x float4,
// shuffle-reduce across slots.
__global__ void k_fused1(const float* __restrict__ el, const float* __restrict__ er,
                         const float* __restrict__ f1, const int* __restrict__ indptr,
                         const int* __restrict__ ecsr, const int* __restrict__ src,
                         const float* __restrict__ b1, float* __restrict__ h1, int N) {
  __shared__ float s_w[4][CAP0];
  __shared__ int s_s[4][CAP0];
  int g = threadIdx.x >> 6;
  int lane = threadIdx.x & 63;
  int n = blockIdx.x * 4 + g;
  int nn = n < N ? n : N - 1;
  int s = indptr[nn], e_ = indptr[nn + 1];
  int deg = e_ - s;
  float er_n = er[nn];
  if (deg <= CAP0) {
    float m = -INFINITY;
    for (int i = lane; i < deg; i += 64) {
      int e = ecsr[s + i];
      int sn = src[e];
      s_s[g][i] = sn;
      float v = el[sn] + er_n;
      v = v >= 0.f ? v : 0.2f * v;
      s_w[g][i] = v;
      m = fmaxf(m, v);
    }
#pragma unroll
    for (int off = 32; off >= 1; off >>= 1) m = fmaxf(m, __shfl_xor(m, off, 64));
    float sum = 0.f;
    for (int i = lane; i < deg; i += 64) {
      float a = expf(s_w[g][i] - m);
      s_w[g][i] = a;
      sum += a;
    }
#pragma unroll
    for (int off = 32; off >= 1; off >>= 1) sum += __shfl_xor(sum, off, 64);
    for (int i = lane; i < deg; i += 64) s_w[g][i] /= sum;
    int es = lane >> 3, q = lane & 7;
    float4 a4 = make_float4(0.f, 0.f, 0.f, 0.f);
    for (int i = es; i < deg; i += 8) {
      float a = s_w[g][i];
      float4 v = ((const float4*)(f1 + (size_t)s_s[g][i] * 32))[q];
      a4.x = fmaf(a, v.x, a4.x); a4.y = fmaf(a, v.y, a4.y);
      a4.z = fmaf(a, v.z, a4.z); a4.w = fmaf(a, v.w, a4.w);
    }
#pragma unroll
    for (int off = 8; off <= 32; off <<= 1) {
      a4.x += __shfl_xor(a4.x, off, 64);
      a4.y += __shfl_xor(a4.y, off, 64);
      a4.z += __shfl_xor(a4.z, off, 64);
      a4.w += __shfl_xor(a4.w, off, 64);
    }
    if (lane < 8 && n < N) {
      float4 b = *(const float4*)(b1 + lane * 4);
      a4.x += b.x; a4.y += b.y; a4.z += b.z; a4.w += b.w;
      ((float4*)(h1 + (size_t)n * 32))[lane] = a4;
    }
  } else {
    float m = -INFINITY;
    for (int i = lane; i < deg; i += 64) {
      float v = el[src[ecsr[s + i]]] + er_n;
      v = v >= 0.f ? v : 0.2f * v;
      m = fmaxf(m, v);
    }
#pragma unroll
    for (int off = 32; off >= 1; off >>= 1) m = fmaxf(m, __shfl_xor(m, off, 64));
    float sum = 0.f;
    for (int i = lane; i < deg; i += 64) {
      float v = el[src[ecsr[s + i]]] + er_n;
      v = v >= 0.f ? v : 0.2f * v;
      sum += expf(v - m);
    }
#pragma unroll
    for (int off = 32; off >= 1; off >>= 1) sum += __shfl_xor(sum, off, 64);
    int d = lane & 31;
    float acc = 0.f;
    if (lane < 32) {
      for (int i = 0; i < deg; ++i) {
        int sn = src[ecsr[s + i]];
        float v = el[sn] + er_n;
        v = v >= 0.f ? v : 0.2f * v;
        float a = expf(v - m) / sum;
        acc = fmaf(a, f1[(size_t)sn * 32 + d], acc);
      }
      if (n < N) h1[(size_t)n * 32 + d] = acc + b1[d];
    }
  }
}

// ---------------- predictor (f64 acc — negligible cost, keeps margin) ----------------
__global__ void k_pred(const float* __restrict__ h1, const float* __restrict__ P1,
                       const float* __restrict__ pb1, const float* __restrict__ P2,
                       const float* __restrict__ pb2, const float* __restrict__ P3,
                       const float* __restrict__ pb3, float* __restrict__ out,
                       int num_edge, int total) {
  int t = threadIdx.x;
  int lane = t & 31, grp = t >> 5;
  int k = blockIdx.x * 8 + grp;
  int kk = k < total ? k : 0;
  float z;
  if (kk < num_edge) {
    z = h1[(size_t)kk * 32 + lane] * h1[(size_t)(kk + num_edge) * 32 + lane];
  } else {
    int i = kk - num_edge;
    z = h1[(size_t)(i % num_edge) * 32 + lane] * h1[(size_t)(2 * num_edge + i) * 32 + lane];
  }
  double a1 = 0;
#pragma unroll
  for (int d = 0; d < 32; ++d)
    a1 += (double)__shfl(z, d, 32) * (double)P1[d * 32 + lane];
  float t1 = (float)(a1 + (double)pb1[lane]);
  t1 = t1 > 0.f ? t1 : 0.f;
  double a2 = 0;
#pragma unroll
  for (int d = 0; d < 32; ++d)
    a2 += (double)__shfl(t1, d, 32) * (double)P2[d * 32 + lane];
  float t2 = (float)(a2 + (double)pb2[lane]);
  t2 = t2 > 0.f ? t2 : 0.f;
  double a3 = (double)t2 * (double)P3[lane];
#pragma unroll
  for (int off = 16; off >= 1; off >>= 1) a3 += __shfl_xor(a3, off, 64);
  if (lane == 0 && k < total) out[k] = (float)(a3 + (double)pb3[0]);
}

extern "C" void kernel_launch(void* const* d_in, const int* in_sizes, int n_in,
                              void* d_out, int out_size, void* d_ws, size_t ws_size,
                              hipStream_t stream) {
  const float* x   = (const float*)d_in[0];
  const int*   src = (const int*)d_in[1];
  const int*   dst = (const int*)d_in[2];
  const float* W0  = (const float*)d_in[4];
  const float* al0 = (const float*)d_in[5];
  const float* ar0 = (const float*)d_in[6];
  const float* b0  = (const float*)d_in[7];
  const float* W1  = (const float*)d_in[8];
  const float* al1 = (const float*)d_in[9];
  const float* ar1 = (const float*)d_in[10];
  const float* b1  = (const float*)d_in[11];
  const float* P1  = (const float*)d_in[12];
  const float* pb1 = (const float*)d_in[13];
  const float* P2  = (const float*)d_in[14];
  const float* pb2 = (const float*)d_in[15];
  const float* P3  = (const float*)d_in[16];
  const float* pb3 = (const float*)d_in[17];

  int N = in_sizes[0] / 128;
  int E = in_sizes[1];
  int num_edge = N - out_size;   // N=(2+r)*ne, out=(1+r)*ne

  size_t off = 0;
  auto alloc = [&](size_t bytes) -> void* {
    void* p = (char*)d_ws + off;
    off += (bytes + 255) & ~(size_t)255;
    return p;
  };
  float* f0     = (float*)alloc((size_t)N * 256 * 4);
  float* hbuf   = (float*)alloc((size_t)N * 256 * 4);
  float* el     = (float*)alloc((size_t)N * 8 * 4);
  float* er     = (float*)alloc((size_t)N * 8 * 4);
  int*   indptr = (int*)alloc((size_t)(N + 1) * 4);
  int*   ecsr   = (int*)alloc((size_t)E * 4);
  int*   counts = (int*)alloc((size_t)N * 4);
  int*   cursor = (int*)alloc((size_t)N * 4);
  int*   partial= (int*)alloc((size_t)N * 4);
  int*   bsums  = (int*)alloc(256 * 4);
  if (off > ws_size) return;
  // aliases (disjoint lifetimes)
  float* f1  = f0;                   // f0 dead after k_fused0
  float* h1  = f0 + (size_t)N * 32;
  float* el1 = el;                   // layer0 el/er dead after k_fused0
  float* er1 = er;

  int gE = (E + 255) / 256;
  int gN = (N + 255) / 256;          // 196 blocks
  hipMemsetAsync(counts, 0, (size_t)N * 4, stream);
  k_hist<<<gE, 256, 0, stream>>>(dst, counts, E);
  k_blockscan<<<gN, 256, 0, stream>>>(counts, partial, bsums, N);
  k_scansums<<<1, 256, 0, stream>>>(bsums, gN);
  k_addoff<<<gN, 256, 0, stream>>>(partial, bsums, counts, indptr, cursor, N);
  k_scatter<<<gE, 256, 0, stream>>>(dst, cursor, ecsr, E);

  k_gemm0<<<(N + 15) / 16, 256, 0, stream>>>(x, W0, al0, ar0, f0, el, er, N);
  k_fused0<<<N, 256, 0, stream>>>(el, er, f0, indptr, ecsr, src, b0, hbuf, N);

  k_gemm1<<<(N + 7) / 8, 256, 0, stream>>>(hbuf, W1, al1, ar1, f1, el1, er1, N);
  k_fused1<<<(N + 3) / 4, 256, 0, stream>>>(el1, er1, f1, indptr, ecsr, src, b1, h1, N);

  k_pred<<<(out_size + 7) / 8, 256, 0, stream>>>(h1, P1, pb1, P2, pb2, P3, pb3,
                                                 (float*)d_out, num_edge, out_size);
}

// Round 8
// 486.749 us; speedup vs baseline: 1.1933x; 1.1933x over previous
//
#include <hip/hip_runtime.h>
#include <cmath>

#ifndef CAP0
#define CAP0 192   // max staged degree; Poisson(16) max ~45. Fallback path covers >CAP.
#endif

// ---------------- CSR build (by dst) ----------------
__global__ void k_hist(const int* __restrict__ dst, int* __restrict__ counts, int E) {
  int e = blockIdx.x * blockDim.x + threadIdx.x;
  if (e < E) atomicAdd(&counts[dst[e]], 1);
}

// inclusive scan within 256-blocks
__global__ void k_blockscan(const int* __restrict__ counts, int* __restrict__ partial,
                            int* __restrict__ bsums, int n) {
  __shared__ int buf[256];
  int tid = threadIdx.x;
  int i = blockIdx.x * 256 + tid;
  int v = (i < n) ? counts[i] : 0;
  buf[tid] = v;
  __syncthreads();
  for (int off = 1; off < 256; off <<= 1) {
    int t = (tid >= off) ? buf[tid - off] : 0;
    __syncthreads();
    buf[tid] += t;
    __syncthreads();
  }
  if (i < n) partial[i] = buf[tid];
  if (tid == 255) bsums[blockIdx.x] = buf[255];
}

// exclusive scan of block sums (nb <= 256), in place
__global__ void k_scansums(int* __restrict__ bsums, int nb) {
  __shared__ int buf[256];
  int tid = threadIdx.x;
  int v = (tid < nb) ? bsums[tid] : 0;
  buf[tid] = v;
  __syncthreads();
  for (int off = 1; off < 256; off <<= 1) {
    int t = (tid >= off) ? buf[tid - off] : 0;
    __syncthreads();
    buf[tid] += t;
    __syncthreads();
  }
  if (tid < nb) bsums[tid] = buf[tid] - v;
}

// indptr[i+1] = inclusive[i]; cursor[i] = exclusive[i] (= running insert ptr for scatter)
__global__ void k_addoff(const int* __restrict__ partial, const int* __restrict__ bsums,
                         const int* __restrict__ counts, int* __restrict__ indptr,
                         int* __restrict__ cursor, int n) {
  int i = blockIdx.x * blockDim.x + threadIdx.x;
  if (i == 0) indptr[0] = 0;
  if (i < n) {
    int incl = partial[i] + bsums[i >> 8];
    indptr[i + 1] = incl;
    cursor[i] = incl - counts[i];
  }
}

// NOTE: bucket order = atomic completion order (nondeterministic). Aggregation
// reorder shifts fp32 sums by ~1e-8 at the final output — accepted.
__global__ void k_scatter(const int* __restrict__ dst, int* __restrict__ cursor,
                          int* __restrict__ ecsr, int E) {
  int e = blockIdx.x * blockDim.x + threadIdx.x;
  if (e < E) {
    int pos = atomicAdd(&cursor[dst[e]], 1);
    ecsr[pos] = e;
  }
}

// ---------------- GEMM0 + fused attention dots (layer 0) ----------------
// f0[N,256] = x[N,128] @ W0[128,256], fp32 4-chunk blocked acc  [R4-exact]
__global__ void k_gemm0(const float* __restrict__ x, const float* __restrict__ W0,
                        const float* __restrict__ al, const float* __restrict__ ar,
                        float* __restrict__ f0, float* __restrict__ el,
                        float* __restrict__ er, int N) {
  int col = threadIdx.x;            // 0..255 == h*32+d
  int row0 = blockIdx.x * 8;
  const float* xr[8];
#pragma unroll
  for (int r = 0; r < 8; ++r) {
    int row = row0 + r; if (row >= N) row = N - 1;
    xr[r] = x + (size_t)row * 128;  // wave-uniform -> scalar loads
  }
  float acc[4][8];
#pragma unroll
  for (int c = 0; c < 4; ++c)
#pragma unroll
    for (int r = 0; r < 8; ++r) acc[c][r] = 0.f;

#pragma unroll
  for (int c = 0; c < 4; ++c) {
    const float* Wc = W0 + (size_t)(c * 32) * 256 + col;
#pragma unroll 4
    for (int kk = 0; kk < 32; ++kk) {
      float w = Wc[kk * 256];
      int k = c * 32 + kk;
#pragma unroll
      for (int r = 0; r < 8; ++r) acc[c][r] = fmaf(xr[r][k], w, acc[c][r]);
    }
  }

  int h = col >> 5;
  float a_l = al[col], a_r = ar[col];
#pragma unroll
  for (int r = 0; r < 8; ++r) {
    int row = row0 + r;
    float f = (acc[0][r] + acc[1][r]) + (acc[2][r] + acc[3][r]);
    if (row < N) f0[(size_t)row * 256 + col] = f;
    float pl = f * a_l;
    float pr = f * a_r;
#pragma unroll
    for (int off = 16; off >= 1; off >>= 1) {
      pl += __shfl_xor(pl, off, 32);
      pr += __shfl_xor(pr, off, 32);
    }
    if ((col & 31) == 0 && row < N) {
      el[row * 8 + h] = pl;
      er[row * 8 + h] = pr;
    }
  }
}

// ---------------- fused edge kernel layer 0 + layer-1 projection ----------------
// one block = one dst node.
// phase 1: scores + segment softmax (8 heads x 32 lanes, LDS);
// phase 2: wave-wide float4 gather (one wave = one full 1 KB f0 row), LDS reduce;
// epilogue: h-row = ELU(agg + b0) stays in LDS (never written to global);
//           f1-row = h_row @ W1 (8x32 partials, W1 is L1-resident) + el1/er1 dots.
__global__ void k_fused0(const float* __restrict__ el, const float* __restrict__ er,
                         const float* __restrict__ f0, const int* __restrict__ indptr,
                         const int* __restrict__ ecsr, const int* __restrict__ src,
                         const float* __restrict__ b0, const float* __restrict__ W1,
                         const float* __restrict__ al1, const float* __restrict__ ar1,
                         float* __restrict__ f1, float* __restrict__ el1,
                         float* __restrict__ er1, int N) {
  __shared__ float s_w[CAP0 * 8];
  __shared__ int s_src[CAP0];
  __shared__ float s_red[4][256];
  __shared__ float s_hrow[256];
  __shared__ float s_p[8][32];
  int n = blockIdx.x;
  int t = threadIdx.x;
  int h = t >> 5, lane = t & 31;
  int s = indptr[n], e_ = indptr[n + 1];
  int deg = e_ - s;
  float er_h = er[n * 8 + h];
  float o;

  if (deg <= CAP0) {
    // ---- phase 1: scores + segment softmax into s_w ----
    float m = -INFINITY;
    for (int i = lane; i < deg; i += 32) {
      int e = ecsr[s + i];
      int sn = src[e];
      if (h == 0) s_src[i] = sn;
      float v = el[sn * 8 + h] + er_h;
      v = v >= 0.f ? v : 0.2f * v;
      s_w[i * 8 + h] = v;
      m = fmaxf(m, v);
    }
#pragma unroll
    for (int off = 16; off >= 1; off >>= 1) m = fmaxf(m, __shfl_xor(m, off, 32));
    float sum = 0.f;
    for (int i = lane; i < deg; i += 32) {
      float a = expf(s_w[i * 8 + h] - m);
      s_w[i * 8 + h] = a;
      sum += a;
    }
#pragma unroll
    for (int off = 16; off >= 1; off >>= 1) sum += __shfl_xor(sum, off, 32);
    for (int i = lane; i < deg; i += 32) s_w[i * 8 + h] /= sum;   // IEEE div as reference
    __syncthreads();

    // ---- phase 2: gather. wave w handles edges w, w+4, ... ----
    int w = t >> 6;
    int l = t & 63;                  // float4 slot: dims 4l..4l+3
    int hh = l >> 3;                 // head of this slot
    float4 a4 = make_float4(0.f, 0.f, 0.f, 0.f);
    int i = w;
    for (; i + 4 < deg; i += 8) {
      float a0 = s_w[i * 8 + hh];
      float a1 = s_w[(i + 4) * 8 + hh];
      float4 v0 = ((const float4*)(f0 + (size_t)s_src[i] * 256))[l];
      float4 v1 = ((const float4*)(f0 + (size_t)s_src[i + 4] * 256))[l];
      a4.x = fmaf(a0, v0.x, a4.x); a4.y = fmaf(a0, v0.y, a4.y);
      a4.z = fmaf(a0, v0.z, a4.z); a4.w = fmaf(a0, v0.w, a4.w);
      a4.x = fmaf(a1, v1.x, a4.x); a4.y = fmaf(a1, v1.y, a4.y);
      a4.z = fmaf(a1, v1.z, a4.z); a4.w = fmaf(a1, v1.w, a4.w);
    }
    if (i < deg) {
      float a0 = s_w[i * 8 + hh];
      float4 v0 = ((const float4*)(f0 + (size_t)s_src[i] * 256))[l];
      a4.x = fmaf(a0, v0.x, a4.x); a4.y = fmaf(a0, v0.y, a4.y);
      a4.z = fmaf(a0, v0.z, a4.z); a4.w = fmaf(a0, v0.w, a4.w);
    }
    ((float4*)s_red[w])[l] = a4;
    __syncthreads();
    o = ((s_red[0][t] + s_red[1][t]) + (s_red[2][t] + s_red[3][t])) + b0[t];
  } else {
    // 3-pass recompute fallback — block-uniform branch
    float m = -INFINITY;
    for (int i = lane; i < deg; i += 32) {
      float v = el[src[ecsr[s + i]] * 8 + h] + er_h;
      v = v >= 0.f ? v : 0.2f * v;
      m = fmaxf(m, v);
    }
#pragma unroll
    for (int off = 16; off >= 1; off >>= 1) m = fmaxf(m, __shfl_xor(m, off, 32));
    float sum = 0.f;
    for (int i = lane; i < deg; i += 32) {
      float v = el[src[ecsr[s + i]] * 8 + h] + er_h;
      v = v >= 0.f ? v : 0.2f * v;
      sum += expf(v - m);
    }
#pragma unroll
    for (int off = 16; off >= 1; off >>= 1) sum += __shfl_xor(sum, off, 32);
    float acc = 0.f;
    for (int i = 0; i < deg; ++i) {
      int sn = src[ecsr[s + i]];
      float v = el[sn * 8 + h] + er_h;
      v = v >= 0.f ? v : 0.2f * v;
      float a = expf(v - m) / sum;
      acc += a * f0[(size_t)sn * 256 + t];
    }
    o = acc + b0[t];
  }

  // ---- epilogue: h-row in LDS; f1 = h @ W1; el1/er1 dots ----
  o = o > 0.f ? o : expm1f(o);   // jax.nn.elu
  s_hrow[t] = o;
  __syncthreads();
  {
    int col = t & 31, g = t >> 5;           // 8 k-groups x 32 cols
    const float* hp = &s_hrow[g * 32];      // broadcast LDS reads
    const float* wp = W1 + (size_t)(g * 32) * 32 + col;
    float p = 0.f;
#pragma unroll 8
    for (int j = 0; j < 32; ++j)
      p = fmaf(hp[j], wp[j * 32], p);
    s_p[g][col] = p;
  }
  __syncthreads();
  if (t < 32) {
    float f = 0.f;
#pragma unroll
    for (int g = 0; g < 8; ++g) f += s_p[g][t];
    float pl = f * al1[t];
    float pr = f * ar1[t];
#pragma unroll
    for (int off = 16; off >= 1; off >>= 1) {
      pl += __shfl_xor(pl, off, 32);
      pr += __shfl_xor(pr, off, 32);
    }
    f1[(size_t)n * 32 + t] = f;
    if (t == 0) { el1[n] = pl; er1[n] = pr; }
  }
}

// ---------------- fused edge kernel layer 1 (H=1, D=32) ----------------
// block = 4 nodes x 64 lanes. agg: 8 edge-slots x 8 lanes x float4,
// shuffle-reduce across slots.
__global__ void k_fused1(const float* __restrict__ el, const float* __restrict__ er,
                         const float* __restrict__ f1, const int* __restrict__ indptr,
                         const int* __restrict__ ecsr, const int* __restrict__ src,
                         const float* __restrict__ b1, float* __restrict__ h1, int N) {
  __shared__ float s_w[4][CAP0];
  __shared__ int s_s[4][CAP0];
  int g = threadIdx.x >> 6;
  int lane = threadIdx.x & 63;
  int n = blockIdx.x * 4 + g;
  int nn = n < N ? n : N - 1;
  int s = indptr[nn], e_ = indptr[nn + 1];
  int deg = e_ - s;
  float er_n = er[nn];
  if (deg <= CAP0) {
    float m = -INFINITY;
    for (int i = lane; i < deg; i += 64) {
      int e = ecsr[s + i];
      int sn = src[e];
      s_s[g][i] = sn;
      float v = el[sn] + er_n;
      v = v >= 0.f ? v : 0.2f * v;
      s_w[g][i] = v;
      m = fmaxf(m, v);
    }
#pragma unroll
    for (int off = 32; off >= 1; off >>= 1) m = fmaxf(m, __shfl_xor(m, off, 64));
    float sum = 0.f;
    for (int i = lane; i < deg; i += 64) {
      float a = expf(s_w[g][i] - m);
      s_w[g][i] = a;
      sum += a;
    }
#pragma unroll
    for (int off = 32; off >= 1; off >>= 1) sum += __shfl_xor(sum, off, 64);
    for (int i = lane; i < deg; i += 64) s_w[g][i] /= sum;
    int es = lane >> 3, q = lane & 7;
    float4 a4 = make_float4(0.f, 0.f, 0.f, 0.f);
    for (int i = es; i < deg; i += 8) {
      float a = s_w[g][i];
      float4 v = ((const float4*)(f1 + (size_t)s_s[g][i] * 32))[q];
      a4.x = fmaf(a, v.x, a4.x); a4.y = fmaf(a, v.y, a4.y);
      a4.z = fmaf(a, v.z, a4.z); a4.w = fmaf(a, v.w, a4.w);
    }
#pragma unroll
    for (int off = 8; off <= 32; off <<= 1) {
      a4.x += __shfl_xor(a4.x, off, 64);
      a4.y += __shfl_xor(a4.y, off, 64);
      a4.z += __shfl_xor(a4.z, off, 64);
      a4.w += __shfl_xor(a4.w, off, 64);
    }
    if (lane < 8 && n < N) {
      float4 b = *(const float4*)(b1 + lane * 4);
      a4.x += b.x; a4.y += b.y; a4.z += b.z; a4.w += b.w;
      ((float4*)(h1 + (size_t)n * 32))[lane] = a4;
    }
  } else {
    float m = -INFINITY;
    for (int i = lane; i < deg; i += 64) {
      float v = el[src[ecsr[s + i]]] + er_n;
      v = v >= 0.f ? v : 0.2f * v;
      m = fmaxf(m, v);
    }
#pragma unroll
    for (int off = 32; off >= 1; off >>= 1) m = fmaxf(m, __shfl_xor(m, off, 64));
    float sum = 0.f;
    for (int i = lane; i < deg; i += 64) {
      float v = el[src[ecsr[s + i]]] + er_n;
      v = v >= 0.f ? v : 0.2f * v;
      sum += expf(v - m);
    }
#pragma unroll
    for (int off = 32; off >= 1; off >>= 1) sum += __shfl_xor(sum, off, 64);
    int d = lane & 31;
    float acc = 0.f;
    if (lane < 32) {
      for (int i = 0; i < deg; ++i) {
        int sn = src[ecsr[s + i]];
        float v = el[sn] + er_n;
        v = v >= 0.f ? v : 0.2f * v;
        float a = expf(v - m) / sum;
        acc = fmaf(a, f1[(size_t)sn * 32 + d], acc);
      }
      if (n < N) h1[(size_t)n * 32 + d] = acc + b1[d];
    }
  }
}

// ---------------- predictor (f64 acc — negligible cost, keeps margin) ----------------
__global__ void k_pred(const float* __restrict__ h1, const float* __restrict__ P1,
                       const float* __restrict__ pb1, const float* __restrict__ P2,
                       const float* __restrict__ pb2, const float* __restrict__ P3,
                       const float* __restrict__ pb3, float* __restrict__ out,
                       int num_edge, int total) {
  int t = threadIdx.x;
  int lane = t & 31, grp = t >> 5;
  int k = blockIdx.x * 8 + grp;
  int kk = k < total ? k : 0;
  float z;
  if (kk < num_edge) {
    z = h1[(size_t)kk * 32 + lane] * h1[(size_t)(kk + num_edge) * 32 + lane];
  } else {
    int i = kk - num_edge;
    z = h1[(size_t)(i % num_edge) * 32 + lane] * h1[(size_t)(2 * num_edge + i) * 32 + lane];
  }
  double a1 = 0;
#pragma unroll
  for (int d = 0; d < 32; ++d)
    a1 += (double)__shfl(z, d, 32) * (double)P1[d * 32 + lane];
  float t1 = (float)(a1 + (double)pb1[lane]);
  t1 = t1 > 0.f ? t1 : 0.f;
  double a2 = 0;
#pragma unroll
  for (int d = 0; d < 32; ++d)
    a2 += (double)__shfl(t1, d, 32) * (double)P2[d * 32 + lane];
  float t2 = (float)(a2 + (double)pb2[lane]);
  t2 = t2 > 0.f ? t2 : 0.f;
  double a3 = (double)t2 * (double)P3[lane];
#pragma unroll
  for (int off = 16; off >= 1; off >>= 1) a3 += __shfl_xor(a3, off, 64);
  if (lane == 0 && k < total) out[k] = (float)(a3 + (double)pb3[0]);
}

extern "C" void kernel_launch(void* const* d_in, const int* in_sizes, int n_in,
                              void* d_out, int out_size, void* d_ws, size_t ws_size,
                              hipStream_t stream) {
  const float* x   = (const float*)d_in[0];
  const int*   src = (const int*)d_in[1];
  const int*   dst = (const int*)d_in[2];
  const float* W0  = (const float*)d_in[4];
  const float* al0 = (const float*)d_in[5];
  const float* ar0 = (const float*)d_in[6];
  const float* b0  = (const float*)d_in[7];
  const float* W1  = (const float*)d_in[8];
  const float* al1 = (const float*)d_in[9];
  const float* ar1 = (const float*)d_in[10];
  const float* b1  = (const float*)d_in[11];
  const float* P1  = (const float*)d_in[12];
  const float* pb1 = (const float*)d_in[13];
  const float* P2  = (const float*)d_in[14];
  const float* pb2 = (const float*)d_in[15];
  const float* P3  = (const float*)d_in[16];
  const float* pb3 = (const float*)d_in[17];

  int N = in_sizes[0] / 128;
  int E = in_sizes[1];
  int num_edge = N - out_size;   // N=(2+r)*ne, out=(1+r)*ne

  size_t off = 0;
  auto alloc = [&](size_t bytes) -> void* {
    void* p = (char*)d_ws + off;
    off += (bytes + 255) & ~(size_t)255;
    return p;
  };
  float* f0     = (float*)alloc((size_t)N * 256 * 4);
  float* f1     = (float*)alloc((size_t)N * 32 * 4);   // written by fused0 (distinct from f0!)
  float* h1     = (float*)alloc((size_t)N * 32 * 4);
  float* el     = (float*)alloc((size_t)N * 8 * 4);
  float* er     = (float*)alloc((size_t)N * 8 * 4);
  float* el1    = (float*)alloc((size_t)N * 4);        // distinct from el (read/write overlap)
  float* er1    = (float*)alloc((size_t)N * 4);
  int*   indptr = (int*)alloc((size_t)(N + 1) * 4);
  int*   ecsr   = (int*)alloc((size_t)E * 4);
  int*   counts = (int*)alloc((size_t)N * 4);
  int*   cursor = (int*)alloc((size_t)N * 4);
  int*   partial= (int*)alloc((size_t)N * 4);
  int*   bsums  = (int*)alloc(256 * 4);
  if (off > ws_size) return;

  int gE = (E + 255) / 256;
  int gN = (N + 255) / 256;          // 196 blocks
  hipMemsetAsync(counts, 0, (size_t)N * 4, stream);
  k_hist<<<gE, 256, 0, stream>>>(dst, counts, E);
  k_blockscan<<<gN, 256, 0, stream>>>(counts, partial, bsums, N);
  k_scansums<<<1, 256, 0, stream>>>(bsums, gN);
  k_addoff<<<gN, 256, 0, stream>>>(partial, bsums, counts, indptr, cursor, N);
  k_scatter<<<gE, 256, 0, stream>>>(dst, cursor, ecsr, E);

  k_gemm0<<<(N + 7) / 8, 256, 0, stream>>>(x, W0, al0, ar0, f0, el, er, N);
  k_fused0<<<N, 256, 0, stream>>>(el, er, f0, indptr, ecsr, src, b0,
                                  W1, al1, ar1, f1, el1, er1, N);
  k_fused1<<<(N + 3) / 4, 256, 0, stream>>>(el1, er1, f1, indptr, ecsr, src, b1, h1, N);

  k_pred<<<(out_size + 7) / 8, 256, 0, stream>>>(h1, P1, pb1, P2, pb2, P3, pb3,
                                                 (float*)d_out, num_edge, out_size);
}

// Round 9
// 461.510 us; speedup vs baseline: 1.2585x; 1.0547x over previous
//
#include <hip/hip_runtime.h>
#include <cmath>

#ifndef CAP0
#define CAP0 192   // max staged degree; Poisson(16) max ~45. Fallback path covers >CAP.
#endif

// ---------------- CSR build (by dst) ----------------
__global__ void k_hist(const int* __restrict__ dst, int* __restrict__ counts, int E) {
  int e = blockIdx.x * blockDim.x + threadIdx.x;
  if (e < E) atomicAdd(&counts[dst[e]], 1);
}

__global__ void k_blockscan(const int* __restrict__ counts, int* __restrict__ partial,
                            int* __restrict__ bsums, int n) {
  __shared__ int buf[256];
  int tid = threadIdx.x;
  int i = blockIdx.x * 256 + tid;
  int v = (i < n) ? counts[i] : 0;
  buf[tid] = v;
  __syncthreads();
  for (int off = 1; off < 256; off <<= 1) {
    int t = (tid >= off) ? buf[tid - off] : 0;
    __syncthreads();
    buf[tid] += t;
    __syncthreads();
  }
  if (i < n) partial[i] = buf[tid];
  if (tid == 255) bsums[blockIdx.x] = buf[255];
}

__global__ void k_scansums(int* __restrict__ bsums, int nb) {
  __shared__ int buf[256];
  int tid = threadIdx.x;
  int v = (tid < nb) ? bsums[tid] : 0;
  buf[tid] = v;
  __syncthreads();
  for (int off = 1; off < 256; off <<= 1) {
    int t = (tid >= off) ? buf[tid - off] : 0;
    __syncthreads();
    buf[tid] += t;
    __syncthreads();
  }
  if (tid < nb) bsums[tid] = buf[tid] - v;
}

// indptr[i+1] = inclusive[i]; cursor[i] = exclusive[i]
__global__ void k_addoff(const int* __restrict__ partial, const int* __restrict__ bsums,
                         const int* __restrict__ counts, int* __restrict__ indptr,
                         int* __restrict__ cursor, int n) {
  int i = blockIdx.x * blockDim.x + threadIdx.x;
  if (i == 0) indptr[0] = 0;
  if (i < n) {
    int incl = partial[i] + bsums[i >> 8];
    indptr[i + 1] = incl;
    cursor[i] = incl - counts[i];
  }
}

// bucket order = atomic completion order (nondeterministic) — fp32 reorder ~1e-8, accepted.
__global__ void k_scatter(const int* __restrict__ dst, int* __restrict__ cursor,
                          int* __restrict__ ecsr, int E) {
  int e = blockIdx.x * blockDim.x + threadIdx.x;
  if (e < E) {
    int pos = atomicAdd(&cursor[dst[e]], 1);
    ecsr[pos] = e;
  }
}

// ---------------- GEMM0 (register-tiled) + fused attention dots ----------------
// f0[N,256] = x[N,128] @ W0[128,256]. Block = 64 rows x 256 cols, 4 waves.
// x staged transposed in LDS ([k][row], pad 68: writes conflict-free, reads are
// wave-broadcast ds_read_b128). Thread = (wave->16 rows, lane->4 cols):
// per k: 1 coalesced W0 float4 + 4 broadcast b128 + 64 FMA.
#define G0_ROWS 64
#define G0_PAD 68
__global__ void k_gemm0(const float* __restrict__ x, const float* __restrict__ W0,
                        const float* __restrict__ al, const float* __restrict__ ar,
                        float* __restrict__ f0, float* __restrict__ el,
                        float* __restrict__ er, int N) {
  __shared__ float s_x[128 * G0_PAD];
  int t = threadIdx.x;
  int w = t >> 6, l = t & 63;
  int row0 = blockIdx.x * G0_ROWS;

  // stage: wave w loads k-range [32w, 32w+32), lane l = row l (row-gather, 16 B/lane)
  {
    int row = row0 + l; if (row >= N) row = N - 1;
    const float* xp = x + (size_t)row * 128 + w * 32;
#pragma unroll
    for (int j = 0; j < 8; ++j) {
      float4 v = *(const float4*)(xp + 4 * j);
      int k = w * 32 + 4 * j;
      s_x[(k + 0) * G0_PAD + l] = v.x;
      s_x[(k + 1) * G0_PAD + l] = v.y;
      s_x[(k + 2) * G0_PAD + l] = v.z;
      s_x[(k + 3) * G0_PAD + l] = v.w;
    }
  }
  __syncthreads();

  float4 acc[16];
#pragma unroll
  for (int r = 0; r < 16; ++r) acc[r] = make_float4(0.f, 0.f, 0.f, 0.f);

  const float* wp = W0 + 4 * l;          // cols 4l..4l+3
  int rbase = w * 16;                    // this wave's rows: row0+rbase .. +15
  for (int k = 0; k < 128; ++k) {
    float4 w4 = *(const float4*)(wp + (size_t)k * 256);
    const float* xk = &s_x[k * G0_PAD + rbase];
    float xv[16];
    *(float4*)&xv[0]  = *(const float4*)(xk);
    *(float4*)&xv[4]  = *(const float4*)(xk + 4);
    *(float4*)&xv[8]  = *(const float4*)(xk + 8);
    *(float4*)&xv[12] = *(const float4*)(xk + 12);
#pragma unroll
    for (int r = 0; r < 16; ++r) {
      acc[r].x = fmaf(xv[r], w4.x, acc[r].x);
      acc[r].y = fmaf(xv[r], w4.y, acc[r].y);
      acc[r].z = fmaf(xv[r], w4.z, acc[r].z);
      acc[r].w = fmaf(xv[r], w4.w, acc[r].w);
    }
  }

  int hh = l >> 3;                       // head of this 4-col group
  float4 al4 = *(const float4*)(al + 4 * l);
  float4 ar4 = *(const float4*)(ar + 4 * l);
#pragma unroll
  for (int r = 0; r < 16; ++r) {
    int row = row0 + rbase + r;
    float4 f = acc[r];
    if (row < N) *(float4*)(f0 + (size_t)row * 256 + 4 * l) = f;
    float pl = fmaf(f.x, al4.x, fmaf(f.y, al4.y, fmaf(f.z, al4.z, f.w * al4.w)));
    float pr = fmaf(f.x, ar4.x, fmaf(f.y, ar4.y, fmaf(f.z, ar4.z, f.w * ar4.w)));
#pragma unroll
    for (int off = 4; off >= 1; off >>= 1) {   // reduce the 8 lanes of one head
      pl += __shfl_xor(pl, off, 64);
      pr += __shfl_xor(pr, off, 64);
    }
    if ((l & 7) == 0 && row < N) {
      el[row * 8 + hh] = pl;
      er[row * 8 + hh] = pr;
    }
  }
}

// ---------------- fused edge kernel layer 0 + layer-1 projection ----------------
__global__ void k_fused0(const float* __restrict__ el, const float* __restrict__ er,
                         const float* __restrict__ f0, const int* __restrict__ indptr,
                         const int* __restrict__ ecsr, const int* __restrict__ src,
                         const float* __restrict__ b0, const float* __restrict__ W1,
                         const float* __restrict__ al1, const float* __restrict__ ar1,
                         float* __restrict__ f1, float* __restrict__ el1,
                         float* __restrict__ er1, int N) {
  __shared__ float s_w[CAP0 * 8];
  __shared__ int s_src[CAP0];
  __shared__ float s_red[4][256];
  __shared__ float s_hrow[256];
  __shared__ float s_p[8][32];
  int n = blockIdx.x;
  int t = threadIdx.x;
  int h = t >> 5, lane = t & 31;
  int s = indptr[n], e_ = indptr[n + 1];
  int deg = e_ - s;
  float er_h = er[n * 8 + h];
  float o;

  if (deg <= CAP0) {
    float m = -INFINITY;
    for (int i = lane; i < deg; i += 32) {
      int e = ecsr[s + i];
      int sn = src[e];
      if (h == 0) s_src[i] = sn;
      float v = el[sn * 8 + h] + er_h;
      v = v >= 0.f ? v : 0.2f * v;
      s_w[i * 8 + h] = v;
      m = fmaxf(m, v);
    }
#pragma unroll
    for (int off = 16; off >= 1; off >>= 1) m = fmaxf(m, __shfl_xor(m, off, 32));
    float sum = 0.f;
    for (int i = lane; i < deg; i += 32) {
      float a = expf(s_w[i * 8 + h] - m);
      s_w[i * 8 + h] = a;
      sum += a;
    }
#pragma unroll
    for (int off = 16; off >= 1; off >>= 1) sum += __shfl_xor(sum, off, 32);
    for (int i = lane; i < deg; i += 32) s_w[i * 8 + h] /= sum;   // IEEE div as reference
    __syncthreads();

    int w = t >> 6;
    int l = t & 63;
    int hh = l >> 3;
    float4 a4 = make_float4(0.f, 0.f, 0.f, 0.f);
    int i = w;
    for (; i + 4 < deg; i += 8) {
      float a0 = s_w[i * 8 + hh];
      float a1 = s_w[(i + 4) * 8 + hh];
      float4 v0 = ((const float4*)(f0 + (size_t)s_src[i] * 256))[l];
      float4 v1 = ((const float4*)(f0 + (size_t)s_src[i + 4] * 256))[l];
      a4.x = fmaf(a0, v0.x, a4.x); a4.y = fmaf(a0, v0.y, a4.y);
      a4.z = fmaf(a0, v0.z, a4.z); a4.w = fmaf(a0, v0.w, a4.w);
      a4.x = fmaf(a1, v1.x, a4.x); a4.y = fmaf(a1, v1.y, a4.y);
      a4.z = fmaf(a1, v1.z, a4.z); a4.w = fmaf(a1, v1.w, a4.w);
    }
    if (i < deg) {
      float a0 = s_w[i * 8 + hh];
      float4 v0 = ((const float4*)(f0 + (size_t)s_src[i] * 256))[l];
      a4.x = fmaf(a0, v0.x, a4.x); a4.y = fmaf(a0, v0.y, a4.y);
      a4.z = fmaf(a0, v0.z, a4.z); a4.w = fmaf(a0, v0.w, a4.w);
    }
    ((float4*)s_red[w])[l] = a4;
    __syncthreads();
    o = ((s_red[0][t] + s_red[1][t]) + (s_red[2][t] + s_red[3][t])) + b0[t];
  } else {
    float m = -INFINITY;
    for (int i = lane; i < deg; i += 32) {
      float v = el[src[ecsr[s + i]] * 8 + h] + er_h;
      v = v >= 0.f ? v : 0.2f * v;
      m = fmaxf(m, v);
    }
#pragma unroll
    for (int off = 16; off >= 1; off >>= 1) m = fmaxf(m, __shfl_xor(m, off, 32));
    float sum = 0.f;
    for (int i = lane; i < deg; i += 32) {
      float v = el[src[ecsr[s + i]] * 8 + h] + er_h;
      v = v >= 0.f ? v : 0.2f * v;
      sum += expf(v - m);
    }
#pragma unroll
    for (int off = 16; off >= 1; off >>= 1) sum += __shfl_xor(sum, off, 32);
    float acc = 0.f;
    for (int i = 0; i < deg; ++i) {
      int sn = src[ecsr[s + i]];
      float v = el[sn * 8 + h] + er_h;
      v = v >= 0.f ? v : 0.2f * v;
      float a = expf(v - m) / sum;
      acc += a * f0[(size_t)sn * 256 + t];
    }
    o = acc + b0[t];
  }

  // epilogue: h-row in LDS; f1 = h @ W1; el1/er1 dots
  o = o > 0.f ? o : expm1f(o);   // jax.nn.elu
  s_hrow[t] = o;
  __syncthreads();
  {
    int col = t & 31, g = t >> 5;
    const float* hp = &s_hrow[g * 32];
    const float* wp = W1 + (size_t)(g * 32) * 32 + col;
    float p = 0.f;
#pragma unroll 8
    for (int j = 0; j < 32; ++j)
      p = fmaf(hp[j], wp[j * 32], p);
    s_p[g][col] = p;
  }
  __syncthreads();
  if (t < 32) {
    float f = 0.f;
#pragma unroll
    for (int g = 0; g < 8; ++g) f += s_p[g][t];
    float pl = f * al1[t];
    float pr = f * ar1[t];
#pragma unroll
    for (int off = 16; off >= 1; off >>= 1) {
      pl += __shfl_xor(pl, off, 32);
      pr += __shfl_xor(pr, off, 32);
    }
    f1[(size_t)n * 32 + t] = f;
    if (t == 0) { el1[n] = pl; er1[n] = pr; }
  }
}

// ---------------- fused edge kernel layer 1 (H=1, D=32) ----------------
__global__ void k_fused1(const float* __restrict__ el, const float* __restrict__ er,
                         const float* __restrict__ f1, const int* __restrict__ indptr,
                         const int* __restrict__ ecsr, const int* __restrict__ src,
                         const float* __restrict__ b1, float* __restrict__ h1, int N) {
  __shared__ float s_w[4][CAP0];
  __shared__ int s_s[4][CAP0];
  int g = threadIdx.x >> 6;
  int lane = threadIdx.x & 63;
  int n = blockIdx.x * 4 + g;
  int nn = n < N ? n : N - 1;
  int s = indptr[nn], e_ = indptr[nn + 1];
  int deg = e_ - s;
  float er_n = er[nn];
  if (deg <= CAP0) {
    float m = -INFINITY;
    for (int i = lane; i < deg; i += 64) {
      int e = ecsr[s + i];
      int sn = src[e];
      s_s[g][i] = sn;
      float v = el[sn] + er_n;
      v = v >= 0.f ? v : 0.2f * v;
      s_w[g][i] = v;
      m = fmaxf(m, v);
    }
#pragma unroll
    for (int off = 32; off >= 1; off >>= 1) m = fmaxf(m, __shfl_xor(m, off, 64));
    float sum = 0.f;
    for (int i = lane; i < deg; i += 64) {
      float a = expf(s_w[g][i] - m);
      s_w[g][i] = a;
      sum += a;
    }
#pragma unroll
    for (int off = 32; off >= 1; off >>= 1) sum += __shfl_xor(sum, off, 64);
    for (int i = lane; i < deg; i += 64) s_w[g][i] /= sum;
    int es = lane >> 3, q = lane & 7;
    float4 a4 = make_float4(0.f, 0.f, 0.f, 0.f);
    for (int i = es; i < deg; i += 8) {
      float a = s_w[g][i];
      float4 v = ((const float4*)(f1 + (size_t)s_s[g][i] * 32))[q];
      a4.x = fmaf(a, v.x, a4.x); a4.y = fmaf(a, v.y, a4.y);
      a4.z = fmaf(a, v.z, a4.z); a4.w = fmaf(a, v.w, a4.w);
    }
#pragma unroll
    for (int off = 8; off <= 32; off <<= 1) {
      a4.x += __shfl_xor(a4.x, off, 64);
      a4.y += __shfl_xor(a4.y, off, 64);
      a4.z += __shfl_xor(a4.z, off, 64);
      a4.w += __shfl_xor(a4.w, off, 64);
    }
    if (lane < 8 && n < N) {
      float4 b = *(const float4*)(b1 + lane * 4);
      a4.x += b.x; a4.y += b.y; a4.z += b.z; a4.w += b.w;
      ((float4*)(h1 + (size_t)n * 32))[lane] = a4;
    }
  } else {
    float m = -INFINITY;
    for (int i = lane; i < deg; i += 64) {
      float v = el[src[ecsr[s + i]]] + er_n;
      v = v >= 0.f ? v : 0.2f * v;
      m = fmaxf(m, v);
    }
#pragma unroll
    for (int off = 32; off >= 1; off >>= 1) m = fmaxf(m, __shfl_xor(m, off, 64));
    float sum = 0.f;
    for (int i = lane; i < deg; i += 64) {
      float v = el[src[ecsr[s + i]]] + er_n;
      v = v >= 0.f ? v : 0.2f * v;
      sum += expf(v - m);
    }
#pragma unroll
    for (int off = 32; off >= 1; off >>= 1) sum += __shfl_xor(sum, off, 64);
    int d = lane & 31;
    float acc = 0.f;
    if (lane < 32) {
      for (int i = 0; i < deg; ++i) {
        int sn = src[ecsr[s + i]];
        float v = el[sn] + er_n;
        v = v >= 0.f ? v : 0.2f * v;
        float a = expf(v - m) / sum;
        acc = fmaf(a, f1[(size_t)sn * 32 + d], acc);
      }
      if (n < N) h1[(size_t)n * 32 + d] = acc + b1[d];
    }
  }
}

// ---------------- predictor (f64 acc — negligible cost, keeps margin) ----------------
__global__ void k_pred(const float* __restrict__ h1, const float* __restrict__ P1,
                       const float* __restrict__ pb1, const float* __restrict__ P2,
                       const float* __restrict__ pb2, const float* __restrict__ P3,
                       const float* __restrict__ pb3, float* __restrict__ out,
                       int num_edge, int total) {
  int t = threadIdx.x;
  int lane = t & 31, grp = t >> 5;
  int k = blockIdx.x * 8 + grp;
  int kk = k < total ? k : 0;
  float z;
  if (kk < num_edge) {
    z = h1[(size_t)kk * 32 + lane] * h1[(size_t)(kk + num_edge) * 32 + lane];
  } else {
    int i = kk - num_edge;
    z = h1[(size_t)(i % num_edge) * 32 + lane] * h1[(size_t)(2 * num_edge + i) * 32 + lane];
  }
  double a1 = 0;
#pragma unroll
  for (int d = 0; d < 32; ++d)
    a1 += (double)__shfl(z, d, 32) * (double)P1[d * 32 + lane];
  float t1 = (float)(a1 + (double)pb1[lane]);
  t1 = t1 > 0.f ? t1 : 0.f;
  double a2 = 0;
#pragma unroll
  for (int d = 0; d < 32; ++d)
    a2 += (double)__shfl(t1, d, 32) * (double)P2[d * 32 + lane];
  float t2 = (float)(a2 + (double)pb2[lane]);
  t2 = t2 > 0.f ? t2 : 0.f;
  double a3 = (double)t2 * (double)P3[lane];
#pragma unroll
  for (int off = 16; off >= 1; off >>= 1) a3 += __shfl_xor(a3, off, 64);
  if (lane == 0 && k < total) out[k] = (float)(a3 + (double)pb3[0]);
}

extern "C" void kernel_launch(void* const* d_in, const int* in_sizes, int n_in,
                              void* d_out, int out_size, void* d_ws, size_t ws_size,
                              hipStream_t stream) {
  const float* x   = (const float*)d_in[0];
  const int*   src = (const int*)d_in[1];
  const int*   dst = (const int*)d_in[2];
  const float* W0  = (const float*)d_in[4];
  const float* al0 = (const float*)d_in[5];
  const float* ar0 = (const float*)d_in[6];
  const float* b0  = (const float*)d_in[7];
  const float* W1  = (const float*)d_in[8];
  const float* al1 = (const float*)d_in[9];
  const float* ar1 = (const float*)d_in[10];
  const float* b1  = (const float*)d_in[11];
  const float* P1  = (const float*)d_in[12];
  const float* pb1 = (const float*)d_in[13];
  const float* P2  = (const float*)d_in[14];
  const float* pb2 = (const float*)d_in[15];
  const float* P3  = (const float*)d_in[16];
  const float* pb3 = (const float*)d_in[17];

  int N = in_sizes[0] / 128;
  int E = in_sizes[1];
  int num_edge = N - out_size;   // N=(2+r)*ne, out=(1+r)*ne

  size_t off = 0;
  auto alloc = [&](size_t bytes) -> void* {
    void* p = (char*)d_ws + off;
    off += (bytes + 255) & ~(size_t)255;
    return p;
  };
  float* f0     = (float*)alloc((size_t)N * 256 * 4);
  float* f1     = (float*)alloc((size_t)N * 32 * 4);
  float* h1     = (float*)alloc((size_t)N * 32 * 4);
  float* el     = (float*)alloc((size_t)N * 8 * 4);
  float* er     = (float*)alloc((size_t)N * 8 * 4);
  float* el1    = (float*)alloc((size_t)N * 4);
  float* er1    = (float*)alloc((size_t)N * 4);
  int*   indptr = (int*)alloc((size_t)(N + 1) * 4);
  int*   ecsr   = (int*)alloc((size_t)E * 4);
  int*   counts = (int*)alloc((size_t)N * 4);
  int*   cursor = (int*)alloc((size_t)N * 4);
  int*   partial= (int*)alloc((size_t)N * 4);
  int*   bsums  = (int*)alloc(256 * 4);
  if (off > ws_size) return;

  int gE = (E + 255) / 256;
  int gN = (N + 255) / 256;          // 196 blocks
  hipMemsetAsync(counts, 0, (size_t)N * 4, stream);
  k_hist<<<gE, 256, 0, stream>>>(dst, counts, E);
  k_blockscan<<<gN, 256, 0, stream>>>(counts, partial, bsums, N);
  k_scansums<<<1, 256, 0, stream>>>(bsums, gN);
  k_addoff<<<gN, 256, 0, stream>>>(partial, bsums, counts, indptr, cursor, N);
  k_scatter<<<gE, 256, 0, stream>>>(dst, cursor, ecsr, E);

  k_gemm0<<<(N + G0_ROWS - 1) / G0_ROWS, 256, 0, stream>>>(x, W0, al0, ar0, f0, el, er, N);
  k_fused0<<<N, 256, 0, stream>>>(el, er, f0, indptr, ecsr, src, b0,
                                  W1, al1, ar1, f1, el1, er1, N);
  k_fused1<<<(N + 3) / 4, 256, 0, stream>>>(el1, er1, f1, indptr, ecsr, src, b1, h1, N);

  k_pred<<<(out_size + 7) / 8, 256, 0, stream>>>(h1, P1, pb1, P2, pb2, P3, pb3,
                                                 (float*)d_out, num_edge, out_size);
}

// Round 10
// 428.528 us; speedup vs baseline: 1.3554x; 1.0770x over previous
//
#include <hip/hip_runtime.h>
#include <cmath>

#define CAPB 96    // padded bucket capacity; deg~Poisson(16), P(>96)~1e-40; overflow list for safety
#define CAP0 192   // max staged degree in fused kernels (bucket + appended overflow)

// ---------------- CSR build: direct padded-bucket scatter ----------------
// cnt[N] zeroed by memset; cnt[N] slot (ovf_cnt) zeroed too (same memset).
__global__ void k_scatter(const int* __restrict__ dst, int* __restrict__ cnt,
                          int* __restrict__ ovf_cnt, int* __restrict__ bpad,
                          int* __restrict__ ovf, int E) {
  int e = blockIdx.x * blockDim.x + threadIdx.x;
  if (e < E) {
    int d = dst[e];
    int pos = atomicAdd(&cnt[d], 1);
    if (pos < CAPB) bpad[(size_t)d * CAPB + pos] = e;
    else { int op = atomicAdd(ovf_cnt, 1); ovf[op] = e; }
  }
}

// ---------------- GEMM0 (register-tiled) + fused attention dots ----------------
// f0[N,256] = x[N,128] @ W0[128,256]. Block = 64 rows x 256 cols, 4 waves.
// x staged transposed in LDS (pad 68). Thread = (wave->16 rows, lane->4 cols).
#define G0_ROWS 64
#define G0_PAD 68
__global__ void k_gemm0(const float* __restrict__ x, const float* __restrict__ W0,
                        const float* __restrict__ al, const float* __restrict__ ar,
                        float* __restrict__ f0, float* __restrict__ el,
                        float* __restrict__ er, int N) {
  __shared__ float s_x[128 * G0_PAD];
  int t = threadIdx.x;
  int w = t >> 6, l = t & 63;
  int row0 = blockIdx.x * G0_ROWS;

  {
    int row = row0 + l; if (row >= N) row = N - 1;
    const float* xp = x + (size_t)row * 128 + w * 32;
#pragma unroll
    for (int j = 0; j < 8; ++j) {
      float4 v = *(const float4*)(xp + 4 * j);
      int k = w * 32 + 4 * j;
      s_x[(k + 0) * G0_PAD + l] = v.x;
      s_x[(k + 1) * G0_PAD + l] = v.y;
      s_x[(k + 2) * G0_PAD + l] = v.z;
      s_x[(k + 3) * G0_PAD + l] = v.w;
    }
  }
  __syncthreads();

  float4 acc[16];
#pragma unroll
  for (int r = 0; r < 16; ++r) acc[r] = make_float4(0.f, 0.f, 0.f, 0.f);

  const float* wp = W0 + 4 * l;
  int rbase = w * 16;
  for (int k = 0; k < 128; ++k) {
    float4 w4 = *(const float4*)(wp + (size_t)k * 256);
    const float* xk = &s_x[k * G0_PAD + rbase];
    float xv[16];
    *(float4*)&xv[0]  = *(const float4*)(xk);
    *(float4*)&xv[4]  = *(const float4*)(xk + 4);
    *(float4*)&xv[8]  = *(const float4*)(xk + 8);
    *(float4*)&xv[12] = *(const float4*)(xk + 12);
#pragma unroll
    for (int r = 0; r < 16; ++r) {
      acc[r].x = fmaf(xv[r], w4.x, acc[r].x);
      acc[r].y = fmaf(xv[r], w4.y, acc[r].y);
      acc[r].z = fmaf(xv[r], w4.z, acc[r].z);
      acc[r].w = fmaf(xv[r], w4.w, acc[r].w);
    }
  }

  int hh = l >> 3;
  float4 al4 = *(const float4*)(al + 4 * l);
  float4 ar4 = *(const float4*)(ar + 4 * l);
#pragma unroll
  for (int r = 0; r < 16; ++r) {
    int row = row0 + rbase + r;
    float4 f = acc[r];
    if (row < N) *(float4*)(f0 + (size_t)row * 256 + 4 * l) = f;
    float pl = fmaf(f.x, al4.x, fmaf(f.y, al4.y, fmaf(f.z, al4.z, f.w * al4.w)));
    float pr = fmaf(f.x, ar4.x, fmaf(f.y, ar4.y, fmaf(f.z, ar4.z, f.w * ar4.w)));
#pragma unroll
    for (int off = 4; off >= 1; off >>= 1) {
      pl += __shfl_xor(pl, off, 64);
      pr += __shfl_xor(pr, off, 64);
    }
    if ((l & 7) == 0 && row < N) {
      el[row * 8 + hh] = pl;
      er[row * 8 + hh] = pr;
    }
  }
}

// ---------------- fused edge kernel layer 0 + layer-1 projection ----------------
// one block = one dst node. phase 0: stage src ids from bucket (+overflow);
// phase 1: scores + segment softmax; phase 2: wave-wide float4 gather;
// epilogue: h-row in LDS -> f1 = h @ W1 + el1/er1 dots.
__global__ void k_fused0(const float* __restrict__ el, const float* __restrict__ er,
                         const float* __restrict__ f0, const int* __restrict__ cnt,
                         const int* __restrict__ ovf_cnt, const int* __restrict__ bpad,
                         const int* __restrict__ ovf, const int* __restrict__ dstp,
                         const int* __restrict__ src, const float* __restrict__ b0,
                         const float* __restrict__ W1, const float* __restrict__ al1,
                         const float* __restrict__ ar1, float* __restrict__ f1,
                         float* __restrict__ el1, float* __restrict__ er1, int N) {
  __shared__ float s_w[CAP0 * 8];
  __shared__ int s_src[CAP0];
  __shared__ float s_red[4][256];
  __shared__ float s_hrow[256];
  __shared__ float s_p[8][32];
  __shared__ int s_deg;
  int n = blockIdx.x;
  int t = threadIdx.x;
  int h = t >> 5, lane = t & 31;

  // ---- phase 0: stage src ids ----
  int cn = cnt[n];
  int degb = cn < CAPB ? cn : CAPB;
  for (int i = t; i < degb; i += 256)
    s_src[i] = src[bpad[(size_t)n * CAPB + i]];
  if (t == 0) {
    int d = degb;
    int ovl = ovf_cnt[0];                 // 0 in practice
    for (int j = 0; j < ovl && d < CAP0; ++j) {
      int e = ovf[j];
      if (dstp[e] == n) s_src[d++] = src[e];
    }
    s_deg = d;
  }
  __syncthreads();
  int deg = s_deg;
  float er_h = er[n * 8 + h];

  // ---- phase 1: scores + segment softmax into s_w ----
  float m = -INFINITY;
  for (int i = lane; i < deg; i += 32) {
    float v = el[s_src[i] * 8 + h] + er_h;
    v = v >= 0.f ? v : 0.2f * v;
    s_w[i * 8 + h] = v;
    m = fmaxf(m, v);
  }
#pragma unroll
  for (int off = 16; off >= 1; off >>= 1) m = fmaxf(m, __shfl_xor(m, off, 32));
  float sum = 0.f;
  for (int i = lane; i < deg; i += 32) {
    float a = expf(s_w[i * 8 + h] - m);
    s_w[i * 8 + h] = a;
    sum += a;
  }
#pragma unroll
  for (int off = 16; off >= 1; off >>= 1) sum += __shfl_xor(sum, off, 32);
  for (int i = lane; i < deg; i += 32) s_w[i * 8 + h] /= sum;   // IEEE div as reference
  __syncthreads();

  // ---- phase 2: gather. wave w handles edges w, w+4, ... ----
  int w = t >> 6;
  int l = t & 63;
  int hh = l >> 3;
  float4 a4 = make_float4(0.f, 0.f, 0.f, 0.f);
  int i = w;
  for (; i + 4 < deg; i += 8) {
    float a0 = s_w[i * 8 + hh];
    float a1 = s_w[(i + 4) * 8 + hh];
    float4 v0 = ((const float4*)(f0 + (size_t)s_src[i] * 256))[l];
    float4 v1 = ((const float4*)(f0 + (size_t)s_src[i + 4] * 256))[l];
    a4.x = fmaf(a0, v0.x, a4.x); a4.y = fmaf(a0, v0.y, a4.y);
    a4.z = fmaf(a0, v0.z, a4.z); a4.w = fmaf(a0, v0.w, a4.w);
    a4.x = fmaf(a1, v1.x, a4.x); a4.y = fmaf(a1, v1.y, a4.y);
    a4.z = fmaf(a1, v1.z, a4.z); a4.w = fmaf(a1, v1.w, a4.w);
  }
  if (i < deg) {
    float a0 = s_w[i * 8 + hh];
    float4 v0 = ((const float4*)(f0 + (size_t)s_src[i] * 256))[l];
    a4.x = fmaf(a0, v0.x, a4.x); a4.y = fmaf(a0, v0.y, a4.y);
    a4.z = fmaf(a0, v0.z, a4.z); a4.w = fmaf(a0, v0.w, a4.w);
  }
  ((float4*)s_red[w])[l] = a4;
  __syncthreads();
  float o = ((s_red[0][t] + s_red[1][t]) + (s_red[2][t] + s_red[3][t])) + b0[t];

  // ---- epilogue: h-row in LDS; f1 = h @ W1; el1/er1 dots ----
  o = o > 0.f ? o : expm1f(o);   // jax.nn.elu
  s_hrow[t] = o;
  __syncthreads();
  {
    int col = t & 31, g = t >> 5;
    const float* hp = &s_hrow[g * 32];
    const float* wp2 = W1 + (size_t)(g * 32) * 32 + col;
    float p = 0.f;
#pragma unroll 8
    for (int j = 0; j < 32; ++j)
      p = fmaf(hp[j], wp2[j * 32], p);
    s_p[g][col] = p;
  }
  __syncthreads();
  if (t < 32) {
    float f = 0.f;
#pragma unroll
    for (int g = 0; g < 8; ++g) f += s_p[g][t];
    float pl = f * al1[t];
    float pr = f * ar1[t];
#pragma unroll
    for (int off = 16; off >= 1; off >>= 1) {
      pl += __shfl_xor(pl, off, 32);
      pr += __shfl_xor(pr, off, 32);
    }
    f1[(size_t)n * 32 + t] = f;
    if (t == 0) { el1[n] = pl; er1[n] = pr; }
  }
}

// ---------------- fused edge kernel layer 1 (H=1, D=32) ----------------
// block = 4 nodes x 64 lanes (wave-synchronous LDS within each wave).
__global__ void k_fused1(const float* __restrict__ el, const float* __restrict__ er,
                         const float* __restrict__ f1, const int* __restrict__ cnt,
                         const int* __restrict__ ovf_cnt, const int* __restrict__ bpad,
                         const int* __restrict__ ovf, const int* __restrict__ dstp,
                         const int* __restrict__ src, const float* __restrict__ b1,
                         float* __restrict__ h1, int N) {
  __shared__ float s_w[4][CAP0];
  __shared__ int s_s[4][CAP0];
  int g = threadIdx.x >> 6;
  int lane = threadIdx.x & 63;
  int n = blockIdx.x * 4 + g;
  int nn = n < N ? n : N - 1;
  int cn = cnt[nn];
  int degb = cn < CAPB ? cn : CAPB;
  float er_n = er[nn];

  for (int i = lane; i < degb; i += 64)
    s_s[g][i] = src[bpad[(size_t)nn * CAPB + i]];
  int deg = degb;
  {
    int ovl = ovf_cnt[0];
    if (ovl) {                            // never in practice
      if (lane == 0) {
        int d = degb;
        for (int j = 0; j < ovl && d < CAP0; ++j) {
          int e = ovf[j];
          if (dstp[e] == nn) s_s[g][d++] = src[e];
        }
        s_w[g][0] = __int_as_float(d);    // stash
      }
      deg = __float_as_int(__shfl(s_w[g][0], 0, 64));
    }
  }

  float m = -INFINITY;
  for (int i = lane; i < deg; i += 64) {
    float v = el[s_s[g][i]] + er_n;
    v = v >= 0.f ? v : 0.2f * v;
    s_w[g][i] = v;
    m = fmaxf(m, v);
  }
#pragma unroll
  for (int off = 32; off >= 1; off >>= 1) m = fmaxf(m, __shfl_xor(m, off, 64));
  float sum = 0.f;
  for (int i = lane; i < deg; i += 64) {
    float a = expf(s_w[g][i] - m);
    s_w[g][i] = a;
    sum += a;
  }
#pragma unroll
  for (int off = 32; off >= 1; off >>= 1) sum += __shfl_xor(sum, off, 64);
  for (int i = lane; i < deg; i += 64) s_w[g][i] /= sum;

  int es = lane >> 3, q = lane & 7;
  float4 a4 = make_float4(0.f, 0.f, 0.f, 0.f);
  for (int i = es; i < deg; i += 8) {
    float a = s_w[g][i];
    float4 v = ((const float4*)(f1 + (size_t)s_s[g][i] * 32))[q];
    a4.x = fmaf(a, v.x, a4.x); a4.y = fmaf(a, v.y, a4.y);
    a4.z = fmaf(a, v.z, a4.z); a4.w = fmaf(a, v.w, a4.w);
  }
#pragma unroll
  for (int off = 8; off <= 32; off <<= 1) {
    a4.x += __shfl_xor(a4.x, off, 64);
    a4.y += __shfl_xor(a4.y, off, 64);
    a4.z += __shfl_xor(a4.z, off, 64);
    a4.w += __shfl_xor(a4.w, off, 64);
  }
  if (lane < 8 && n < N) {
    float4 b = *(const float4*)(b1 + lane * 4);
    a4.x += b.x; a4.y += b.y; a4.z += b.z; a4.w += b.w;
    ((float4*)(h1 + (size_t)n * 32))[lane] = a4;
  }
}

// ---------------- predictor (f64 acc — negligible cost, keeps margin) ----------------
__global__ void k_pred(const float* __restrict__ h1, const float* __restrict__ P1,
                       const float* __restrict__ pb1, const float* __restrict__ P2,
                       const float* __restrict__ pb2, const float* __restrict__ P3,
                       const float* __restrict__ pb3, float* __restrict__ out,
                       int num_edge, int total) {
  int t = threadIdx.x;
  int lane = t & 31, grp = t >> 5;
  int k = blockIdx.x * 8 + grp;
  int kk = k < total ? k : 0;
  float z;
  if (kk < num_edge) {
    z = h1[(size_t)kk * 32 + lane] * h1[(size_t)(kk + num_edge) * 32 + lane];
  } else {
    int i = kk - num_edge;
    z = h1[(size_t)(i % num_edge) * 32 + lane] * h1[(size_t)(2 * num_edge + i) * 32 + lane];
  }
  double a1 = 0;
#pragma unroll
  for (int d = 0; d < 32; ++d)
    a1 += (double)__shfl(z, d, 32) * (double)P1[d * 32 + lane];
  float t1 = (float)(a1 + (double)pb1[lane]);
  t1 = t1 > 0.f ? t1 : 0.f;
  double a2 = 0;
#pragma unroll
  for (int d = 0; d < 32; ++d)
    a2 += (double)__shfl(t1, d, 32) * (double)P2[d * 32 + lane];
  float t2 = (float)(a2 + (double)pb2[lane]);
  t2 = t2 > 0.f ? t2 : 0.f;
  double a3 = (double)t2 * (double)P3[lane];
#pragma unroll
  for (int off = 16; off >= 1; off >>= 1) a3 += __shfl_xor(a3, off, 64);
  if (lane == 0 && k < total) out[k] = (float)(a3 + (double)pb3[0]);
}

extern "C" void kernel_launch(void* const* d_in, const int* in_sizes, int n_in,
                              void* d_out, int out_size, void* d_ws, size_t ws_size,
                              hipStream_t stream) {
  const float* x   = (const float*)d_in[0];
  const int*   src = (const int*)d_in[1];
  const int*   dst = (const int*)d_in[2];
  const float* W0  = (const float*)d_in[4];
  const float* al0 = (const float*)d_in[5];
  const float* ar0 = (const float*)d_in[6];
  const float* b0  = (const float*)d_in[7];
  const float* W1  = (const float*)d_in[8];
  const float* al1 = (const float*)d_in[9];
  const float* ar1 = (const float*)d_in[10];
  const float* b1  = (const float*)d_in[11];
  const float* P1  = (const float*)d_in[12];
  const float* pb1 = (const float*)d_in[13];
  const float* P2  = (const float*)d_in[14];
  const float* pb2 = (const float*)d_in[15];
  const float* P3  = (const float*)d_in[16];
  const float* pb3 = (const float*)d_in[17];

  int N = in_sizes[0] / 128;
  int E = in_sizes[1];
  int num_edge = N - out_size;   // N=(2+r)*ne, out=(1+r)*ne

  size_t off = 0;
  auto alloc = [&](size_t bytes) -> void* {
    void* p = (char*)d_ws + off;
    off += (bytes + 255) & ~(size_t)255;
    return p;
  };
  float* f0   = (float*)alloc((size_t)N * 256 * 4);
  float* f1   = (float*)alloc((size_t)N * 32 * 4);
  float* h1   = (float*)alloc((size_t)N * 32 * 4);
  float* el   = (float*)alloc((size_t)N * 8 * 4);
  float* er   = (float*)alloc((size_t)N * 8 * 4);
  float* el1  = (float*)alloc((size_t)N * 4);
  float* er1  = (float*)alloc((size_t)N * 4);
  int*   cnt  = (int*)alloc((size_t)(N + 1) * 4);   // [N] = overflow counter
  int*   bpad = (int*)alloc((size_t)N * CAPB * 4);
  int*   ovf  = (int*)alloc((size_t)E * 4);
  if (off > ws_size) return;
  int* ovf_cnt = cnt + N;

  int gE = (E + 255) / 256;
  hipMemsetAsync(cnt, 0, (size_t)(N + 1) * 4, stream);
  k_scatter<<<gE, 256, 0, stream>>>(dst, cnt, ovf_cnt, bpad, ovf, E);

  k_gemm0<<<(N + G0_ROWS - 1) / G0_ROWS, 256, 0, stream>>>(x, W0, al0, ar0, f0, el, er, N);
  k_fused0<<<N, 256, 0, stream>>>(el, er, f0, cnt, ovf_cnt, bpad, ovf, dst, src, b0,
                                  W1, al1, ar1, f1, el1, er1, N);
  k_fused1<<<(N + 3) / 4, 256, 0, stream>>>(el1, er1, f1, cnt, ovf_cnt, bpad, ovf, dst,
                                            src, b1, h1, N);
  k_pred<<<(out_size + 7) / 8, 256, 0, stream>>>(h1, P1, pb1, P2, pb2, P3, pb3,
                                                 (float*)d_out, num_edge, out_size);
}

// Round 11
// 415.717 us; speedup vs baseline: 1.3972x; 1.0308x over previous
//
#include <hip/hip_runtime.h>
#include <cmath>

#define CAPB 96    // padded bucket capacity; deg~Poisson(16), P(>96)~1e-40; overflow list for safety
#define CAP0 192   // max staged degree in fused kernels (bucket + appended overflow)
#define G0_ROWS 64
#define G0_PAD 68

// ---------------- merged: edge scatter (all blocks) + GEMM0 tile (first blocks) ----------
// Buckets store the SRC node id directly (scatter reads src[e] coalesced); overflow
// list stores the edge id (needs dst recheck later). Scatter is memory/atomic-bound,
// gemm0 is VALU-bound -> co-resident overlap inside one dispatch.
__global__ void k_gemm0_scatter(const float* __restrict__ x, const float* __restrict__ W0,
                                const float* __restrict__ al, const float* __restrict__ ar,
                                const int* __restrict__ dst, const int* __restrict__ src,
                                float* __restrict__ f0, float* __restrict__ el,
                                float* __restrict__ er, int* __restrict__ cnt,
                                int* __restrict__ ovf_cnt, int* __restrict__ bpad,
                                int* __restrict__ ovf, int N, int E) {
  __shared__ float s_x[128 * G0_PAD];
  int t = threadIdx.x;

  // ---- scatter share (grid-stride, all blocks) ----
  for (int e = blockIdx.x * blockDim.x + t; e < E; e += gridDim.x * blockDim.x) {
    int d = dst[e];
    int pos = atomicAdd(&cnt[d], 1);
    if (pos < CAPB) bpad[(size_t)d * CAPB + pos] = src[e];
    else { int op = atomicAdd(ovf_cnt, 1); ovf[op] = e; }
  }

  // ---- gemm0 tile (block-uniform branch) ----
  if (blockIdx.x >= (N + G0_ROWS - 1) / G0_ROWS) return;
  int w = t >> 6, l = t & 63;
  int row0 = blockIdx.x * G0_ROWS;
  {
    int row = row0 + l; if (row >= N) row = N - 1;
    const float* xp = x + (size_t)row * 128 + w * 32;
#pragma unroll
    for (int j = 0; j < 8; ++j) {
      float4 v = *(const float4*)(xp + 4 * j);
      int k = w * 32 + 4 * j;
      s_x[(k + 0) * G0_PAD + l] = v.x;
      s_x[(k + 1) * G0_PAD + l] = v.y;
      s_x[(k + 2) * G0_PAD + l] = v.z;
      s_x[(k + 3) * G0_PAD + l] = v.w;
    }
  }
  __syncthreads();

  float4 acc[16];
#pragma unroll
  for (int r = 0; r < 16; ++r) acc[r] = make_float4(0.f, 0.f, 0.f, 0.f);

  const float* wp = W0 + 4 * l;
  int rbase = w * 16;
  for (int k = 0; k < 128; ++k) {
    float4 w4 = *(const float4*)(wp + (size_t)k * 256);
    const float* xk = &s_x[k * G0_PAD + rbase];
    float xv[16];
    *(float4*)&xv[0]  = *(const float4*)(xk);
    *(float4*)&xv[4]  = *(const float4*)(xk + 4);
    *(float4*)&xv[8]  = *(const float4*)(xk + 8);
    *(float4*)&xv[12] = *(const float4*)(xk + 12);
#pragma unroll
    for (int r = 0; r < 16; ++r) {
      acc[r].x = fmaf(xv[r], w4.x, acc[r].x);
      acc[r].y = fmaf(xv[r], w4.y, acc[r].y);
      acc[r].z = fmaf(xv[r], w4.z, acc[r].z);
      acc[r].w = fmaf(xv[r], w4.w, acc[r].w);
    }
  }

  int hh = l >> 3;
  float4 al4 = *(const float4*)(al + 4 * l);
  float4 ar4 = *(const float4*)(ar + 4 * l);
#pragma unroll
  for (int r = 0; r < 16; ++r) {
    int row = row0 + rbase + r;
    float4 f = acc[r];
    if (row < N) *(float4*)(f0 + (size_t)row * 256 + 4 * l) = f;
    float pl = fmaf(f.x, al4.x, fmaf(f.y, al4.y, fmaf(f.z, al4.z, f.w * al4.w)));
    float pr = fmaf(f.x, ar4.x, fmaf(f.y, ar4.y, fmaf(f.z, ar4.z, f.w * ar4.w)));
#pragma unroll
    for (int off = 4; off >= 1; off >>= 1) {
      pl += __shfl_xor(pl, off, 64);
      pr += __shfl_xor(pr, off, 64);
    }
    if ((l & 7) == 0 && row < N) {
      el[row * 8 + hh] = pl;
      er[row * 8 + hh] = pr;
    }
  }
}

// ---------------- fused edge kernel layer 0 + layer-1 projection ----------------
__global__ void k_fused0(const float* __restrict__ el, const float* __restrict__ er,
                         const float* __restrict__ f0, const int* __restrict__ cnt,
                         const int* __restrict__ ovf_cnt, const int* __restrict__ bpad,
                         const int* __restrict__ ovf, const int* __restrict__ dstp,
                         const int* __restrict__ src, const float* __restrict__ b0,
                         const float* __restrict__ W1, const float* __restrict__ al1,
                         const float* __restrict__ ar1, float* __restrict__ f1,
                         float* __restrict__ el1, float* __restrict__ er1, int N) {
  __shared__ float s_w[CAP0 * 8];
  __shared__ int s_src[CAP0];
  __shared__ float s_red[4][256];
  __shared__ float s_hrow[256];
  __shared__ float s_p[8][32];
  __shared__ int s_deg;
  int n = blockIdx.x;
  int t = threadIdx.x;
  int h = t >> 5, lane = t & 31;

  // ---- phase 0: stage src ids (buckets hold src directly) ----
  int cn = cnt[n];
  int degb = cn < CAPB ? cn : CAPB;
  for (int i = t; i < degb; i += 256)
    s_src[i] = bpad[(size_t)n * CAPB + i];
  if (t == 0) {
    int d = degb;
    int ovl = ovf_cnt[0];                 // 0 in practice
    for (int j = 0; j < ovl && d < CAP0; ++j) {
      int e = ovf[j];
      if (dstp[e] == n) s_src[d++] = src[e];
    }
    s_deg = d;
  }
  __syncthreads();
  int deg = s_deg;
  float er_h = er[n * 8 + h];

  // ---- phase 1: scores + segment softmax into s_w ----
  float m = -INFINITY;
  for (int i = lane; i < deg; i += 32) {
    float v = el[s_src[i] * 8 + h] + er_h;
    v = v >= 0.f ? v : 0.2f * v;
    s_w[i * 8 + h] = v;
    m = fmaxf(m, v);
  }
#pragma unroll
  for (int off = 16; off >= 1; off >>= 1) m = fmaxf(m, __shfl_xor(m, off, 32));
  float sum = 0.f;
  for (int i = lane; i < deg; i += 32) {
    float a = expf(s_w[i * 8 + h] - m);
    s_w[i * 8 + h] = a;
    sum += a;
  }
#pragma unroll
  for (int off = 16; off >= 1; off >>= 1) sum += __shfl_xor(sum, off, 32);
  for (int i = lane; i < deg; i += 32) s_w[i * 8 + h] /= sum;   // IEEE div as reference
  __syncthreads();

  // ---- phase 2: gather. wave w handles edges w, w+4, ... ----
  int w = t >> 6;
  int l = t & 63;
  int hh = l >> 3;
  float4 a4 = make_float4(0.f, 0.f, 0.f, 0.f);
  int i = w;
  for (; i + 4 < deg; i += 8) {
    float a0 = s_w[i * 8 + hh];
    float a1 = s_w[(i + 4) * 8 + hh];
    float4 v0 = ((const float4*)(f0 + (size_t)s_src[i] * 256))[l];
    float4 v1 = ((const float4*)(f0 + (size_t)s_src[i + 4] * 256))[l];
    a4.x = fmaf(a0, v0.x, a4.x); a4.y = fmaf(a0, v0.y, a4.y);
    a4.z = fmaf(a0, v0.z, a4.z); a4.w = fmaf(a0, v0.w, a4.w);
    a4.x = fmaf(a1, v1.x, a4.x); a4.y = fmaf(a1, v1.y, a4.y);
    a4.z = fmaf(a1, v1.z, a4.z); a4.w = fmaf(a1, v1.w, a4.w);
  }
  if (i < deg) {
    float a0 = s_w[i * 8 + hh];
    float4 v0 = ((const float4*)(f0 + (size_t)s_src[i] * 256))[l];
    a4.x = fmaf(a0, v0.x, a4.x); a4.y = fmaf(a0, v0.y, a4.y);
    a4.z = fmaf(a0, v0.z, a4.z); a4.w = fmaf(a0, v0.w, a4.w);
  }
  ((float4*)s_red[w])[l] = a4;
  __syncthreads();
  float o = ((s_red[0][t] + s_red[1][t]) + (s_red[2][t] + s_red[3][t])) + b0[t];

  // ---- epilogue: h-row in LDS; f1 = h @ W1; el1/er1 dots ----
  o = o > 0.f ? o : expm1f(o);   // jax.nn.elu
  s_hrow[t] = o;
  __syncthreads();
  {
    int col = t & 31, g = t >> 5;
    const float* hp = &s_hrow[g * 32];
    const float* wp2 = W1 + (size_t)(g * 32) * 32 + col;
    float p = 0.f;
#pragma unroll 8
    for (int j = 0; j < 32; ++j)
      p = fmaf(hp[j], wp2[j * 32], p);
    s_p[g][col] = p;
  }
  __syncthreads();
  if (t < 32) {
    float f = 0.f;
#pragma unroll
    for (int g = 0; g < 8; ++g) f += s_p[g][t];
    float pl = f * al1[t];
    float pr = f * ar1[t];
#pragma unroll
    for (int off = 16; off >= 1; off >>= 1) {
      pl += __shfl_xor(pl, off, 32);
      pr += __shfl_xor(pr, off, 32);
    }
    f1[(size_t)n * 32 + t] = f;
    if (t == 0) { el1[n] = pl; er1[n] = pr; }
  }
}

// ---------------- fused edge kernel layer 1 (H=1, D=32) ----------------
__global__ void k_fused1(const float* __restrict__ el, const float* __restrict__ er,
                         const float* __restrict__ f1, const int* __restrict__ cnt,
                         const int* __restrict__ ovf_cnt, const int* __restrict__ bpad,
                         const int* __restrict__ ovf, const int* __restrict__ dstp,
                         const int* __restrict__ src, const float* __restrict__ b1,
                         float* __restrict__ h1, int N) {
  __shared__ float s_w[4][CAP0];
  __shared__ int s_s[4][CAP0];
  int g = threadIdx.x >> 6;
  int lane = threadIdx.x & 63;
  int n = blockIdx.x * 4 + g;
  int nn = n < N ? n : N - 1;
  int cn = cnt[nn];
  int degb = cn < CAPB ? cn : CAPB;
  float er_n = er[nn];

  for (int i = lane; i < degb; i += 64)
    s_s[g][i] = bpad[(size_t)nn * CAPB + i];
  int deg = degb;
  {
    int ovl = ovf_cnt[0];
    if (ovl) {                            // never in practice
      if (lane == 0) {
        int d = degb;
        for (int j = 0; j < ovl && d < CAP0; ++j) {
          int e = ovf[j];
          if (dstp[e] == nn) s_s[g][d++] = src[e];
        }
        s_w[g][0] = __int_as_float(d);    // stash
      }
      deg = __float_as_int(__shfl(s_w[g][0], 0, 64));
    }
  }

  float m = -INFINITY;
  for (int i = lane; i < deg; i += 64) {
    float v = el[s_s[g][i]] + er_n;
    v = v >= 0.f ? v : 0.2f * v;
    s_w[g][i] = v;
    m = fmaxf(m, v);
  }
#pragma unroll
  for (int off = 32; off >= 1; off >>= 1) m = fmaxf(m, __shfl_xor(m, off, 64));
  float sum = 0.f;
  for (int i = lane; i < deg; i += 64) {
    float a = expf(s_w[g][i] - m);
    s_w[g][i] = a;
    sum += a;
  }
#pragma unroll
  for (int off = 32; off >= 1; off >>= 1) sum += __shfl_xor(sum, off, 64);
  for (int i = lane; i < deg; i += 64) s_w[g][i] /= sum;

  int es = lane >> 3, q = lane & 7;
  float4 a4 = make_float4(0.f, 0.f, 0.f, 0.f);
  for (int i = es; i < deg; i += 8) {
    float a = s_w[g][i];
    float4 v = ((const float4*)(f1 + (size_t)s_s[g][i] * 32))[q];
    a4.x = fmaf(a, v.x, a4.x); a4.y = fmaf(a, v.y, a4.y);
    a4.z = fmaf(a, v.z, a4.z); a4.w = fmaf(a, v.w, a4.w);
  }
#pragma unroll
  for (int off = 8; off <= 32; off <<= 1) {
    a4.x += __shfl_xor(a4.x, off, 64);
    a4.y += __shfl_xor(a4.y, off, 64);
    a4.z += __shfl_xor(a4.z, off, 64);
    a4.w += __shfl_xor(a4.w, off, 64);
  }
  if (lane < 8 && n < N) {
    float4 b = *(const float4*)(b1 + lane * 4);
    a4.x += b.x; a4.y += b.y; a4.z += b.z; a4.w += b.w;
    ((float4*)(h1 + (size_t)n * 32))[lane] = a4;
  }
}

// ---------------- predictor (f64 acc — negligible cost, keeps margin) ----------------
__global__ void k_pred(const float* __restrict__ h1, const float* __restrict__ P1,
                       const float* __restrict__ pb1, const float* __restrict__ P2,
                       const float* __restrict__ pb2, const float* __restrict__ P3,
                       const float* __restrict__ pb3, float* __restrict__ out,
                       int num_edge, int total) {
  int t = threadIdx.x;
  int lane = t & 31, grp = t >> 5;
  int k = blockIdx.x * 8 + grp;
  int kk = k < total ? k : 0;
  float z;
  if (kk < num_edge) {
    z = h1[(size_t)kk * 32 + lane] * h1[(size_t)(kk + num_edge) * 32 + lane];
  } else {
    int i = kk - num_edge;
    z = h1[(size_t)(i % num_edge) * 32 + lane] * h1[(size_t)(2 * num_edge + i) * 32 + lane];
  }
  double a1 = 0;
#pragma unroll
  for (int d = 0; d < 32; ++d)
    a1 += (double)__shfl(z, d, 32) * (double)P1[d * 32 + lane];
  float t1 = (float)(a1 + (double)pb1[lane]);
  t1 = t1 > 0.f ? t1 : 0.f;
  double a2 = 0;
#pragma unroll
  for (int d = 0; d < 32; ++d)
    a2 += (double)__shfl(t1, d, 32) * (double)P2[d * 32 + lane];
  float t2 = (float)(a2 + (double)pb2[lane]);
  t2 = t2 > 0.f ? t2 : 0.f;
  double a3 = (double)t2 * (double)P3[lane];
#pragma unroll
  for (int off = 16; off >= 1; off >>= 1) a3 += __shfl_xor(a3, off, 64);
  if (lane == 0 && k < total) out[k] = (float)(a3 + (double)pb3[0]);
}

extern "C" void kernel_launch(void* const* d_in, const int* in_sizes, int n_in,
                              void* d_out, int out_size, void* d_ws, size_t ws_size,
                              hipStream_t stream) {
  const float* x   = (const float*)d_in[0];
  const int*   src = (const int*)d_in[1];
  const int*   dst = (const int*)d_in[2];
  const float* W0  = (const float*)d_in[4];
  const float* al0 = (const float*)d_in[5];
  const float* ar0 = (const float*)d_in[6];
  const float* b0  = (const float*)d_in[7];
  const float* W1  = (const float*)d_in[8];
  const float* al1 = (const float*)d_in[9];
  const float* ar1 = (const float*)d_in[10];
  const float* b1  = (const float*)d_in[11];
  const float* P1  = (const float*)d_in[12];
  const float* pb1 = (const float*)d_in[13];
  const float* P2  = (const float*)d_in[14];
  const float* pb2 = (const float*)d_in[15];
  const float* P3  = (const float*)d_in[16];
  const float* pb3 = (const float*)d_in[17];

  int N = in_sizes[0] / 128;
  int E = in_sizes[1];
  int num_edge = N - out_size;   // N=(2+r)*ne, out=(1+r)*ne

  size_t off = 0;
  auto alloc = [&](size_t bytes) -> void* {
    void* p = (char*)d_ws + off;
    off += (bytes + 255) & ~(size_t)255;
    return p;
  };
  float* f0   = (float*)alloc((size_t)N * 256 * 4);
  float* f1   = (float*)alloc((size_t)N * 32 * 4);
  float* h1   = (float*)alloc((size_t)N * 32 * 4);
  float* el   = (float*)alloc((size_t)N * 8 * 4);
  float* er   = (float*)alloc((size_t)N * 8 * 4);
  float* el1  = (float*)alloc((size_t)N * 4);
  float* er1  = (float*)alloc((size_t)N * 4);
  int*   cnt  = (int*)alloc((size_t)(N + 1) * 4);   // [N] = overflow counter
  int*   bpad = (int*)alloc((size_t)N * CAPB * 4);
  int*   ovf  = (int*)alloc((size_t)E * 4);
  if (off > ws_size) return;
  int* ovf_cnt = cnt + N;

  hipMemsetAsync(cnt, 0, (size_t)(N + 1) * 4, stream);
  k_gemm0_scatter<<<1024, 256, 0, stream>>>(x, W0, al0, ar0, dst, src,
                                            f0, el, er, cnt, ovf_cnt, bpad, ovf, N, E);
  k_fused0<<<N, 256, 0, stream>>>(el, er, f0, cnt, ovf_cnt, bpad, ovf, dst, src, b0,
                                  W1, al1, ar1, f1, el1, er1, N);
  k_fused1<<<(N + 3) / 4, 256, 0, stream>>>(el1, er1, f1, cnt, ovf_cnt, bpad, ovf, dst,
                                            src, b1, h1, N);
  k_pred<<<(out_size + 7) / 8, 256, 0, stream>>>(h1, P1, pb1, P2, pb2, P3, pb3,
                                                 (float*)d_out, num_edge, out_size);
}